// Round 11
// baseline (483.254 us; speedup 1.0000x reference)
//
#include <hip/hip_runtime.h>

#define DI __device__ __forceinline__

DI float bf2f(unsigned short u){ unsigned int v = ((unsigned int)u)<<16; float f; __builtin_memcpy(&f,&v,4); return f; }
DI unsigned short f2bf(float f){ unsigned int v; __builtin_memcpy(&v,&f,4); v = v + 0x7FFFu + ((v>>16)&1u); return (unsigned short)(v>>16); }

typedef __attribute__((ext_vector_type(8))) short bf16x8;
typedef __attribute__((ext_vector_type(4))) float f32x4;

#define GLD_LDS16(src, dst) __builtin_amdgcn_global_load_lds( \
    (const __attribute__((address_space(1))) void*)(src), \
    (__attribute__((address_space(3))) void*)(dst), 16, 0, 0)

DI void barrier_() { asm volatile("" ::: "memory"); __builtin_amdgcn_s_barrier(); asm volatile("" ::: "memory"); }

// ---------------- gemm6: enc1 with FUSED f32->bf16 A-conversion ----------------
// A f32 [M][lda=2000], logical K=2048 (cols >=2000 are zero). B bf16 [N][2048].
// 256x256 tile, 512 thr, dbuf, reg-staged A (convert in-register), gld_lds B.
// One barrier + vmcnt(0) per tile; 64 MFMA/tile/wave cover the load latency.
template<int ACT>
__global__ __launch_bounds__(512) void gemm6_k(
    const float* __restrict__ A, const unsigned short* __restrict__ Bt,
    const float* __restrict__ bias, unsigned short* __restrict__ C,
    int lda, int ldb, int ldc)
{
  __shared__ unsigned short As[2][16384];
  __shared__ unsigned short Bs[2][16384];
  const int tid = threadIdx.x, lane = tid & 63, wid = tid >> 6;
  const int wm = wid >> 2, wn = wid & 3;
  const int q = lane >> 4, r15 = lane & 15;
  const int nx = gridDim.x;
  const int bid = blockIdx.x + nx*blockIdx.y;
  const int cpx = (nx*gridDim.y) >> 3;
  const int wg = (bid & 7)*cpx + (bid >> 3);
  const long long mBase = (long long)(wg / nx) << 8;
  const long long nBase = (long long)(wg % nx) << 8;

  f32x4 acc[8][4];
#pragma unroll
  for (int i=0;i<8;i++)
#pragma unroll
    for (int j=0;j<4;j++)
#pragma unroll
      for (int r=0;r<4;r++) acc[i][j][r] = 0.f;

  const int NT = 32;           // K = 2048
  float4 aL[8];

#define G6_LDA(kk) { _Pragma("unroll") for (int j=0;j<4;j++){ \
    const int d_ = tid + (j<<9); const int row_ = d_>>3, cc_ = d_&7; \
    const int col8 = (kk) + (cc_<<3); \
    if (col8 < 2000) { \
      const float* p_ = A + (mBase+row_)*(long long)lda + col8; \
      aL[2*j] = *(const float4*)p_; aL[2*j+1] = *(const float4*)(p_+4); \
    } else { aL[2*j] = make_float4(0.f,0.f,0.f,0.f); aL[2*j+1] = make_float4(0.f,0.f,0.f,0.f); } } }
#define G6_WRA(nb) { _Pragma("unroll") for (int j=0;j<4;j++){ \
    const int d_ = tid + (j<<9); const int row_ = d_>>3, cc_ = d_&7; const int sc_ = cc_ ^ (row_&7); \
    bf16x8 v_; \
    v_[0]=(short)f2bf(aL[2*j].x);   v_[1]=(short)f2bf(aL[2*j].y); \
    v_[2]=(short)f2bf(aL[2*j].z);   v_[3]=(short)f2bf(aL[2*j].w); \
    v_[4]=(short)f2bf(aL[2*j+1].x); v_[5]=(short)f2bf(aL[2*j+1].y); \
    v_[6]=(short)f2bf(aL[2*j+1].z); v_[7]=(short)f2bf(aL[2*j+1].w); \
    *(bf16x8*)&As[nb][(d_>>3<<6) + (sc_<<3)] = v_; } }
#define G6_STB(nb, kk) { _Pragma("unroll") for (int j=0;j<4;j++){ \
    const int d_ = tid + (j<<9); const int row_ = d_>>3, c_ = d_&7, sc_ = c_ ^ (row_&7); \
    GLD_LDS16(Bt + (nBase+row_)*(long long)ldb + (kk) + (sc_<<3), &Bs[nb][d_<<3]); } }

  // prologue: tile 0
  G6_LDA(0);
  G6_STB(0, 0);
  asm volatile("s_waitcnt vmcnt(0)" ::: "memory");
  G6_WRA(0);
  __syncthreads();

  for (int t=0; t<NT; ++t) {
    const int b = t & 1, nb = b ^ 1;
    const bool more = (t+1 < NT);
    const int k1 = (t+1) << 6;
    // issue next-tile loads so they overlap this tile's compute
    if (more) { G6_LDA(k1); G6_STB(nb, k1); }

    bf16x8 aF[8], bL[4], bH[4];
#pragma unroll
    for (int mi=0; mi<4; ++mi)
#pragma unroll
      for (int ks=0; ks<2; ++ks) {
        const int row = (wm<<7) + (mi<<4) + r15;
        const int ch = ((ks<<2)+q) ^ (row&7);
        aF[mi*2+ks] = *(const bf16x8*)&As[b][(row<<6) + (ch<<3)];
      }
#pragma unroll
    for (int ni=0; ni<2; ++ni)
#pragma unroll
      for (int ks=0; ks<2; ++ks) {
        const int colL = (wn<<6) + (ni<<4) + r15;
        const int colH = (wn<<6) + ((ni+2)<<4) + r15;
        bL[ni*2+ks] = *(const bf16x8*)&Bs[b][(colL<<6) + ((((ks<<2)+q) ^ (colL&7))<<3)];
        bH[ni*2+ks] = *(const bf16x8*)&Bs[b][(colH<<6) + ((((ks<<2)+q) ^ (colH&7))<<3)];
      }
    __builtin_amdgcn_s_setprio(1);
#pragma unroll
    for (int mi=0; mi<4; ++mi)
#pragma unroll
      for (int ni=0; ni<2; ++ni)
#pragma unroll
        for (int ks=0; ks<2; ++ks) {
          acc[mi][ni]   = __builtin_amdgcn_mfma_f32_16x16x32_bf16(aF[mi*2+ks], bL[ni*2+ks], acc[mi][ni],   0,0,0);
          acc[mi][ni+2] = __builtin_amdgcn_mfma_f32_16x16x32_bf16(aF[mi*2+ks], bH[ni*2+ks], acc[mi][ni+2], 0,0,0);
        }
    __builtin_amdgcn_s_setprio(0);
#pragma unroll
    for (int mi=0; mi<4; ++mi)
#pragma unroll
      for (int ks=0; ks<2; ++ks) {
        const int row = (wm<<7) + ((mi+4)<<4) + r15;
        const int ch = ((ks<<2)+q) ^ (row&7);
        aF[mi*2+ks] = *(const bf16x8*)&As[b][(row<<6) + (ch<<3)];
      }
    __builtin_amdgcn_s_setprio(1);
#pragma unroll
    for (int mi=0; mi<4; ++mi)
#pragma unroll
      for (int ni=0; ni<2; ++ni)
#pragma unroll
        for (int ks=0; ks<2; ++ks) {
          acc[mi+4][ni]   = __builtin_amdgcn_mfma_f32_16x16x32_bf16(aF[mi*2+ks], bL[ni*2+ks], acc[mi+4][ni],   0,0,0);
          acc[mi+4][ni+2] = __builtin_amdgcn_mfma_f32_16x16x32_bf16(aF[mi*2+ks], bH[ni*2+ks], acc[mi+4][ni+2], 0,0,0);
        }
    __builtin_amdgcn_s_setprio(0);

    if (more) {
      asm volatile("s_waitcnt vmcnt(0)" ::: "memory");  // A regs + B LDS landed
      G6_WRA(nb);
    }
    __syncthreads();
  }
#undef G6_LDA
#undef G6_WRA
#undef G6_STB

#pragma unroll
  for (int ni=0; ni<4; ++ni) {
    const long long n = nBase + (wn<<6) + (ni<<4) + r15;
    const float bval = bias[n];
#pragma unroll
    for (int mi=0; mi<8; ++mi) {
#pragma unroll
      for (int r=0; r<4; ++r) {
        const long long m = mBase + (wm<<7) + (mi<<4) + (q<<2) + r;
        float v = acc[mi][ni][r] + bval;
        if constexpr (ACT==1) v = fmaxf(v, 0.f);
        C[m*(long long)ldc + n] = f2bf(v);
      }
    }
  }
}

// ---------------- gemm5: 128x128 tile, 4-phase counted-vmcnt pipeline ----------------
template<int ACT>
__global__ __launch_bounds__(256,2) void gemm5_k(
    const unsigned short* __restrict__ A, const unsigned short* __restrict__ Bt,
    const float* __restrict__ bias, unsigned short* __restrict__ C,
    int K, int lda, int ldb, int ldc)
{
  __shared__ unsigned short As[2][8192];
  __shared__ unsigned short Bs[2][8192];
  const int tid = threadIdx.x, lane = tid & 63, wid = tid >> 6;
  const int wm = wid >> 1, wn = wid & 1;
  const int q = lane >> 4, r15 = lane & 15;
  const int nx = gridDim.x;
  const int bid = blockIdx.x + nx*blockIdx.y;
  const int cpx = (nx*gridDim.y) >> 3;
  const int wg = (bid & 7)*cpx + (bid >> 3);
  const long long mBase = (long long)(wg / nx) << 7;
  const long long nBase = (long long)(wg % nx) << 7;

  f32x4 acc[4][4];
#pragma unroll
  for (int i=0;i<4;i++)
#pragma unroll
    for (int j=0;j<4;j++)
#pragma unroll
      for (int r=0;r<4;r++) acc[i][j][r] = 0.f;

  const int NT = K >> 6;

#define G5_STA(j, nb, kk) { const int d_ = tid + ((j)<<8); const int row_ = d_>>3, c_ = d_&7, sc_ = c_ ^ (row_&7); \
    GLD_LDS16(A + (mBase+row_)*(long long)lda + (kk) + (sc_<<3), &As[nb][d_<<3]); }
#define G5_STB(j, nb, kk) { const int d_ = tid + ((j)<<8); const int row_ = d_>>3, c_ = d_&7, sc_ = c_ ^ (row_&7); \
    GLD_LDS16(Bt + (nBase+row_)*(long long)ldb + (kk) + (sc_<<3), &Bs[nb][d_<<3]); }

  G5_STB(0,0,0); G5_STB(2,0,0); G5_STB(1,0,0); G5_STB(3,0,0);
  G5_STA(0,0,0); G5_STA(2,0,0); G5_STA(1,0,0); G5_STA(3,0,0);

  for (int t=0; t<NT; ++t) {
    const int b = t & 1, nb = b ^ 1;
    const bool more = (t+1 < NT);
    const int k1 = (t+1) << 6;
    bf16x8 aL[4], aH[4], bL[4], bH[4];

    asm volatile("s_waitcnt vmcnt(2)" ::: "memory");
    barrier_();
#pragma unroll
    for (int mi=0; mi<2; ++mi)
#pragma unroll
      for (int ks=0; ks<2; ++ks) {
        const int row = (wm<<6) + (mi<<4) + r15;
        const int ch = ((ks<<2)+q) ^ (row&7);
        aL[mi*2+ks] = *(const bf16x8*)&As[b][(row<<6) + (ch<<3)];
      }
#pragma unroll
    for (int ni=0; ni<2; ++ni)
#pragma unroll
      for (int ks=0; ks<2; ++ks) {
        const int col = (wn<<6) + (ni<<4) + r15;
        const int ch = ((ks<<2)+q) ^ (col&7);
        bL[ni*2+ks] = *(const bf16x8*)&Bs[b][(col<<6) + (ch<<3)];
      }
    if (more) { G5_STB(0,nb,k1); G5_STB(2,nb,k1); }
    __builtin_amdgcn_s_setprio(1);
#pragma unroll
    for (int mi=0; mi<2; ++mi)
#pragma unroll
      for (int ni=0; ni<2; ++ni)
#pragma unroll
        for (int ks=0; ks<2; ++ks)
          acc[mi][ni] = __builtin_amdgcn_mfma_f32_16x16x32_bf16(aL[mi*2+ks], bL[ni*2+ks], acc[mi][ni], 0,0,0);
    __builtin_amdgcn_s_setprio(0);
    barrier_();

#pragma unroll
    for (int ni=0; ni<2; ++ni)
#pragma unroll
      for (int ks=0; ks<2; ++ks) {
        const int col = (wn<<6) + ((ni+2)<<4) + r15;
        const int ch = ((ks<<2)+q) ^ (col&7);
        bH[ni*2+ks] = *(const bf16x8*)&Bs[b][(col<<6) + (ch<<3)];
      }
    if (more) { G5_STB(1,nb,k1); G5_STB(3,nb,k1); }
    __builtin_amdgcn_s_setprio(1);
#pragma unroll
    for (int mi=0; mi<2; ++mi)
#pragma unroll
      for (int ni=0; ni<2; ++ni)
#pragma unroll
        for (int ks=0; ks<2; ++ks)
          acc[mi][ni+2] = __builtin_amdgcn_mfma_f32_16x16x32_bf16(aL[mi*2+ks], bH[ni*2+ks], acc[mi][ni+2], 0,0,0);
    __builtin_amdgcn_s_setprio(0);

    if (more) { asm volatile("s_waitcnt vmcnt(4)" ::: "memory"); }
    else      { asm volatile("s_waitcnt vmcnt(0)" ::: "memory"); }
    barrier_();
#pragma unroll
    for (int mi=0; mi<2; ++mi)
#pragma unroll
      for (int ks=0; ks<2; ++ks) {
        const int row = (wm<<6) + ((mi+2)<<4) + r15;
        const int ch = ((ks<<2)+q) ^ (row&7);
        aH[mi*2+ks] = *(const bf16x8*)&As[b][(row<<6) + (ch<<3)];
      }
    if (more) { G5_STA(0,nb,k1); G5_STA(2,nb,k1); }
    __builtin_amdgcn_s_setprio(1);
#pragma unroll
    for (int mi=0; mi<2; ++mi)
#pragma unroll
      for (int ni=0; ni<2; ++ni)
#pragma unroll
        for (int ks=0; ks<2; ++ks)
          acc[mi+2][ni] = __builtin_amdgcn_mfma_f32_16x16x32_bf16(aH[mi*2+ks], bL[ni*2+ks], acc[mi+2][ni], 0,0,0);
    __builtin_amdgcn_s_setprio(0);
    barrier_();

    if (more) { G5_STA(1,nb,k1); G5_STA(3,nb,k1); }
    __builtin_amdgcn_s_setprio(1);
#pragma unroll
    for (int mi=0; mi<2; ++mi)
#pragma unroll
      for (int ni=0; ni<2; ++ni)
#pragma unroll
        for (int ks=0; ks<2; ++ks)
          acc[mi+2][ni+2] = __builtin_amdgcn_mfma_f32_16x16x32_bf16(aH[mi*2+ks], bH[ni*2+ks], acc[mi+2][ni+2], 0,0,0);
    __builtin_amdgcn_s_setprio(0);
  }
#undef G5_STA
#undef G5_STB

#pragma unroll
  for (int ni=0; ni<4; ++ni) {
    const long long n = nBase + (wn<<6) + (ni<<4) + r15;
    const float bval = bias[n];
#pragma unroll
    for (int mi=0; mi<4; ++mi) {
#pragma unroll
      for (int r=0; r<4; ++r) {
        const long long m = mBase + (wm<<6) + (mi<<4) + (q<<2) + r;
        float v = acc[mi][ni][r] + bval;
        if constexpr (ACT==1) v = fmaxf(v, 0.f);
        C[m*(long long)ldc + n] = f2bf(v);
      }
    }
  }
}

// ---------------- gemm4: 256x256 tile, 4-phase counted-vmcnt pipeline (MoE) ----------------
template<int ACT, bool MOE>
__global__ __launch_bounds__(512,2) void gemm4_k(
    const unsigned short* __restrict__ A, const unsigned short* __restrict__ Bt,
    const float* __restrict__ bias, unsigned short* __restrict__ C,
    const float* __restrict__ w2, float* __restrict__ scp,
    int K, int lda, int ldb, int ldc)
{
  __shared__ unsigned short As[2][16384];
  __shared__ unsigned short Bs[2][16384];
  const int tid = threadIdx.x, lane = tid & 63, wid = tid >> 6;
  const int wm = wid >> 2, wn = wid & 3;
  const int q = lane >> 4, r15 = lane & 15;
  const int nx = gridDim.x;
  const int bid = blockIdx.x + nx*blockIdx.y;
  const int cpx = (nx*gridDim.y) >> 3;
  const int wg = (bid & 7)*cpx + (bid >> 3);
  const long long mBase = (long long)(wg / nx) << 8;
  const long long nBase = (long long)(wg % nx) << 8;

  f32x4 acc[8][4];
#pragma unroll
  for (int i=0;i<8;i++)
#pragma unroll
    for (int j=0;j<4;j++)
#pragma unroll
      for (int r=0;r<4;r++) acc[i][j][r] = 0.f;

  const int NT = K >> 6;

#define G4_STA(j, nb, kk) { const int d_ = tid + ((j)<<9); const int row_ = d_>>3, c_ = d_&7, sc_ = c_ ^ (row_&7); \
    GLD_LDS16(A + (mBase+row_)*(long long)lda + (kk) + (sc_<<3), &As[nb][d_<<3]); }
#define G4_STB(j, nb, kk) { const int d_ = tid + ((j)<<9); const int row_ = d_>>3, c_ = d_&7, sc_ = c_ ^ (row_&7); \
    GLD_LDS16(Bt + (nBase+row_)*(long long)ldb + (kk) + (sc_<<3), &Bs[nb][d_<<3]); }

  G4_STB(0,0,0); G4_STB(1,0,0); G4_STB(2,0,0); G4_STB(3,0,0);
  G4_STA(0,0,0); G4_STA(2,0,0); G4_STA(1,0,0); G4_STA(3,0,0);

  for (int t=0; t<NT; ++t) {
    const int b = t & 1, nb = b ^ 1;
    const bool more = (t+1 < NT);
    const int k1 = (t+1) << 6;
    bf16x8 aF[8], bL[4], bH[4];

    asm volatile("s_waitcnt vmcnt(2)" ::: "memory");
    barrier_();
#pragma unroll
    for (int mi=0; mi<4; ++mi)
#pragma unroll
      for (int ks=0; ks<2; ++ks) {
        const int row = (wm<<7) + (mi<<4) + r15;
        const int ch = ((ks<<2)+q) ^ (row&7);
        aF[mi*2+ks] = *(const bf16x8*)&As[b][(row<<6) + (ch<<3)];
      }
#pragma unroll
    for (int ni=0; ni<2; ++ni)
#pragma unroll
      for (int ks=0; ks<2; ++ks) {
        const int col = (wn<<6) + (ni<<4) + r15;
        const int ch = ((ks<<2)+q) ^ (col&7);
        bL[ni*2+ks] = *(const bf16x8*)&Bs[b][(col<<6) + (ch<<3)];
      }
    if (more) { G4_STB(0,nb,k1); G4_STB(1,nb,k1); }
    __builtin_amdgcn_s_setprio(1);
#pragma unroll
    for (int mi=0; mi<4; ++mi)
#pragma unroll
      for (int ni=0; ni<2; ++ni)
#pragma unroll
        for (int ks=0; ks<2; ++ks)
          acc[mi][ni] = __builtin_amdgcn_mfma_f32_16x16x32_bf16(aF[mi*2+ks], bL[ni*2+ks], acc[mi][ni], 0,0,0);
    __builtin_amdgcn_s_setprio(0);
    barrier_();

#pragma unroll
    for (int ni=0; ni<2; ++ni)
#pragma unroll
      for (int ks=0; ks<2; ++ks) {
        const int col = (wn<<6) + ((ni+2)<<4) + r15;
        const int ch = ((ks<<2)+q) ^ (col&7);
        bH[ni*2+ks] = *(const bf16x8*)&Bs[b][(col<<6) + (ch<<3)];
      }
    if (more) { G4_STB(2,nb,k1); G4_STB(3,nb,k1); }
    __builtin_amdgcn_s_setprio(1);
#pragma unroll
    for (int mi=0; mi<4; ++mi)
#pragma unroll
      for (int ni=0; ni<2; ++ni)
#pragma unroll
        for (int ks=0; ks<2; ++ks)
          acc[mi][ni+2] = __builtin_amdgcn_mfma_f32_16x16x32_bf16(aF[mi*2+ks], bH[ni*2+ks], acc[mi][ni+2], 0,0,0);
    __builtin_amdgcn_s_setprio(0);

    if (more) { asm volatile("s_waitcnt vmcnt(4)" ::: "memory"); }
    else      { asm volatile("s_waitcnt vmcnt(0)" ::: "memory"); }
    barrier_();
#pragma unroll
    for (int mi=0; mi<4; ++mi)
#pragma unroll
      for (int ks=0; ks<2; ++ks) {
        const int row = (wm<<7) + ((mi+4)<<4) + r15;
        const int ch = ((ks<<2)+q) ^ (row&7);
        aF[mi*2+ks] = *(const bf16x8*)&As[b][(row<<6) + (ch<<3)];
      }
    if (more) { G4_STA(0,nb,k1); G4_STA(2,nb,k1); }
    __builtin_amdgcn_s_setprio(1);
#pragma unroll
    for (int mi=0; mi<4; ++mi)
#pragma unroll
      for (int ni=0; ni<2; ++ni)
#pragma unroll
        for (int ks=0; ks<2; ++ks)
          acc[mi+4][ni] = __builtin_amdgcn_mfma_f32_16x16x32_bf16(aF[mi*2+ks], bL[ni*2+ks], acc[mi+4][ni], 0,0,0);
    __builtin_amdgcn_s_setprio(0);
    barrier_();

    if (more) { G4_STA(1,nb,k1); G4_STA(3,nb,k1); }
    __builtin_amdgcn_s_setprio(1);
#pragma unroll
    for (int mi=0; mi<4; ++mi)
#pragma unroll
      for (int ni=0; ni<2; ++ni)
#pragma unroll
        for (int ks=0; ks<2; ++ks)
          acc[mi+4][ni+2] = __builtin_amdgcn_mfma_f32_16x16x32_bf16(aF[mi*2+ks], bH[ni*2+ks], acc[mi+4][ni+2], 0,0,0);
    __builtin_amdgcn_s_setprio(0);
  }
#undef G4_STA
#undef G4_STB

  if constexpr (MOE) {
    const int e = (int)(nBase >> 8);
#pragma unroll
    for (int mi=0; mi<8; ++mi) {
#pragma unroll
      for (int r=0; r<4; ++r) {
        float p = 0.f;
#pragma unroll
        for (int ni=0; ni<4; ++ni) {
          const int n = (int)nBase + (wn<<6) + (ni<<4) + r15;
          const float v = acc[mi][ni][r] + bias[n];
          const float th = 1.f - 2.f/(__expf(2.f*v) + 1.f);
          p += th * w2[n];
        }
        p += __shfl_xor(p,1,64); p += __shfl_xor(p,2,64);
        p += __shfl_xor(p,4,64); p += __shfl_xor(p,8,64);
        if (r15 == 0) {
          const long long m = mBase + (wm<<7) + (mi<<4) + (q<<2) + r;
          atomicAdd(scp + ((long long)e<<14) + m, p);
        }
      }
    }
  } else {
#pragma unroll
    for (int ni=0; ni<4; ++ni) {
      const long long n = nBase + (wn<<6) + (ni<<4) + r15;
      const float bval = bias[n];
#pragma unroll
      for (int mi=0; mi<8; ++mi) {
#pragma unroll
        for (int r=0; r<4; ++r) {
          const long long m = mBase + (wm<<7) + (mi<<4) + (q<<2) + r;
          float v = acc[mi][ni][r] + bval;
          if constexpr (ACT==1) v = fmaxf(v, 0.f);
          C[m*(long long)ldc + n] = f2bf(v);
        }
      }
    }
  }
}

// ---------------- prep: t1 + weight transposes + qkvb (round-8 form, no x) ----------------
DI void transpose64(const float* __restrict__ src, unsigned short* __restrict__ dst,
                    int K, int N, int Kpad, int k0, int n0, float (*tile)[65], int tid)
{
  const int c = tid & 63, rg = tid >> 6;
#pragma unroll
  for (int j=0;j<16;j++){
    const int r = (j<<2) + rg;
    const int k = k0 + r;
    tile[r][c] = (k < K) ? src[(long long)k*N + n0 + c] : 0.f;
  }
  __syncthreads();
#pragma unroll
  for (int j=0;j<16;j++){
    const int nn = (j<<2) + rg;
    dst[(long long)(n0+nn)*Kpad + k0 + c] = f2bf(tile[c][nn]);
  }
}

__global__ __launch_bounds__(256) void prep_k(
    const float* __restrict__ enc_w1, unsigned short* __restrict__ w1t,
    const float* __restrict__ enc_w2, unsigned short* __restrict__ w2t,
    const float* __restrict__ enc_w3, const float* __restrict__ q_w,
    const float* __restrict__ k_w, const float* __restrict__ v_w, const float* __restrict__ o_w,
    unsigned short* __restrict__ w3t, unsigned short* __restrict__ qkvw, unsigned short* __restrict__ owt,
    const float* __restrict__ moe_w1, unsigned short* __restrict__ mwt,
    const float* __restrict__ Ew, const float* __restrict__ Fw, float* __restrict__ t1,
    const float* __restrict__ qb, const float* __restrict__ kb, const float* __restrict__ vb,
    float* __restrict__ qkvb)
{
  __shared__ float tile[64][65];
  const int b = blockIdx.x, tid = threadIdx.x;
  if (b < 512) {
    const int k = b & 255, which = b >> 8, c = tid;
    const float* Wr = (which ? Fw : Ew) + (long long)c*10000;
    const float ksc = 39.0625f, inv = 1.f/39.0625f;
    const float sf = (k + 0.5f)*ksc - 0.5f;
    int ilo = (int)ceilf(sf - ksc); if (ilo < 0) ilo = 0;
    int ihi = (int)floorf(sf + ksc); if (ihi > 9999) ihi = 9999;
    float acc = 0.f, wsum = 0.f;
    int i = ilo;
    for (; i + 8 <= ihi + 1; i += 8) {
      float v[8];
#pragma unroll
      for (int j=0;j<8;j++) v[j] = Wr[i+j];
#pragma unroll
      for (int j=0;j<8;j++){
        const float w = fmaxf(1.f - fabsf(sf - (float)(i+j))*inv, 0.f);
        acc += w*v[j]; wsum += w;
      }
    }
    for (; i <= ihi; ++i) {
      const float w = fmaxf(1.f - fabsf(sf - (float)i)*inv, 0.f);
      acc += w * Wr[i]; wsum += w;
    }
    t1[(which*256 + k)*256 + c] = acc / wsum;
  } else if (b < 1024) {
    const int bb = b - 512;
    transpose64(enc_w1, w1t, 2000, 1024, 2048, (bb&31)<<6, (bb>>5)<<6, tile, tid);
  } else if (b < 1152) {
    const int bb = b - 1024;
    transpose64(enc_w2, w2t, 1024, 512, 1024, (bb&15)<<6, (bb>>4)<<6, tile, tid);
  } else if (b < 1472) {
    const int bb = b - 1152;
    const int z = bb >> 6, r = bb & 63;
    const float* s = (z==0)?enc_w3:(z==1)?q_w:(z==2)?k_w:(z==3)?v_w:o_w;
    unsigned short* d = (z==0)?w3t:(z==1)?qkvw:(z==2)?(qkvw+512*512):(z==3)?(qkvw+1024*512):owt;
    transpose64(s, d, 512, 512, 512, (r&7)<<6, (r>>3)<<6, tile, tid);
  } else if (b < 1600) {
    const int bb = b - 1472;
    const int z = bb >> 5, r = bb & 31;
    transpose64(moe_w1 + (long long)z*512*256, mwt + (long long)z*256*512,
                512, 256, 512, (r&7)<<6, (r>>3)<<6, tile, tid);
  } else {
#pragma unroll
    for (int i=0;i<6;i++){
      const int idx = i*256 + tid;
      const int wq = idx >> 9, off = idx & 511;
      const float* src = (wq==0)?qb:(wq==1)?kb:vb;
      qkvb[idx] = src[off];
    }
  }
}

// ---------------- linformer projection helpers ----------------
__global__ __launch_bounds__(512) void red_k(const unsigned short* __restrict__ qkv,
                                             float* __restrict__ red)
{
  const int c = blockIdx.x, which = blockIdx.y, j = threadIdx.x;
  const unsigned short* X = qkv + (which ? 1024 : 512);
  int nlo = 64*c - 32; if (nlo < 0) nlo = 0;
  int nhi = 64*c + 95; if (nhi > 16383) nhi = 16383;
  float acc = 0.f;
  for (int n=nlo; n<=nhi; ++n) {
    float sf = (n + 0.5f)*0.015625f - 0.5f;
    sf = fminf(fmaxf(sf, 0.f), 255.f);
    const int c0 = (int)sf;
    const float f = sf - (float)c0;
    float w = 0.f;
    if (c == c0) w = 1.f - f;
    else if (c == c0+1) w = f;
    if (w != 0.f) acc += w * bf2f(X[(long long)n*1536 + j]);
  }
  red[(which*256 + c)*512 + j] = acc;
}

__global__ __launch_bounds__(512) void kc_k(const float* __restrict__ t1, const float* __restrict__ red,
                                            unsigned short* __restrict__ Kc, unsigned short* __restrict__ Vct)
{
  const int k = blockIdx.x, which = blockIdx.y, j = threadIdx.x;
  const float* T = t1 + (which*256 + k)*256;
  const float* R = red + which*131072;
  float acc = 0.f;
  for (int c=0; c<256; ++c) acc += T[c] * R[c*512 + j];
  const int h = j >> 6, d = j & 63;
  if (which == 0) Kc [(h<<14) + (k<<6) + d] = f2bf(acc);
  else            Vct[(h<<14) + (d<<8) + k] = f2bf(acc);
}

// ---------------- fused linformer attention ----------------
__global__ __launch_bounds__(256) void attn_k(
    const unsigned short* __restrict__ Qg, const unsigned short* __restrict__ Kc,
    const unsigned short* __restrict__ Vct, unsigned short* __restrict__ ao)
{
  __shared__ unsigned short Ks[16384];
  __shared__ unsigned short Vs[16384];
  __shared__ unsigned short Ps[32768];
  const int h = blockIdx.y;
  const long long mBase = (long long)blockIdx.x << 7;
  const int tid = threadIdx.x, lane = tid & 63, wid = tid >> 6;
  const int q = lane >> 4, r15 = lane & 15;

#pragma unroll
  for (int it=0; it<8; ++it) {
    const int dbase = (it<<8) + (wid<<6);
    const int d = dbase + lane;
    {
      const int row = d >> 3, cc = d & 7, sc = cc ^ (row & 7);
      GLD_LDS16(Kc + (h<<14) + (row<<6) + (sc<<3), Ks + (dbase<<3));
    }
    {
      const int row = d >> 5, cc = d & 31, sc = (cc & 24) | ((cc ^ (row & 7)) & 7);
      GLD_LDS16(Vct + (h<<14) + (row<<8) + (sc<<3), Vs + (dbase<<3));
    }
  }
  __syncthreads();

  f32x4 acc[2][16];
#pragma unroll
  for (int mi=0;mi<2;mi++)
#pragma unroll
    for (int ni=0;ni<16;ni++)
#pragma unroll
      for (int r=0;r<4;r++) acc[mi][ni][r] = 0.f;

#pragma unroll
  for (int ks=0; ks<2; ++ks) {
    bf16x8 af[2];
#pragma unroll
    for (int mi=0; mi<2; ++mi) {
      const long long m = mBase + (wid<<5) + (mi<<4) + r15;
      af[mi] = *(const bf16x8*)(Qg + m*1536 + (h<<6) + (ks<<5) + (q<<3));
    }
#pragma unroll
    for (int ni=0; ni<16; ++ni) {
      const int col = (ni<<4) + r15;
      const int ch = ((ks<<2)+q) ^ (col&7);
      const bf16x8 bv = *(const bf16x8*)(Ks + (col<<6) + (ch<<3));
      acc[0][ni] = __builtin_amdgcn_mfma_f32_16x16x32_bf16(af[0], bv, acc[0][ni], 0,0,0);
      acc[1][ni] = __builtin_amdgcn_mfma_f32_16x16x32_bf16(af[1], bv, acc[1][ni], 0,0,0);
    }
  }

#pragma unroll
  for (int mi=0; mi<2; ++mi) {
#pragma unroll
    for (int r=0; r<4; ++r) {
      float mx = -3.4e38f;
#pragma unroll
      for (int ni=0; ni<16; ++ni) mx = fmaxf(mx, acc[mi][ni][r]);
      mx = fmaxf(mx, __shfl_xor(mx,1,64)); mx = fmaxf(mx, __shfl_xor(mx,2,64));
      mx = fmaxf(mx, __shfl_xor(mx,4,64)); mx = fmaxf(mx, __shfl_xor(mx,8,64));
      float s = 0.f;
#pragma unroll
      for (int ni=0; ni<16; ++ni) {
        const float e = __expf((acc[mi][ni][r] - mx)*0.125f);
        acc[mi][ni][r] = e; s += e;
      }
      s += __shfl_xor(s,1,64); s += __shfl_xor(s,2,64);
      s += __shfl_xor(s,4,64); s += __shfl_xor(s,8,64);
      const float inv = 1.f / s;
      const int row = (wid<<5) + (mi<<4) + (q<<2) + r;
#pragma unroll
      for (int ni=0; ni<16; ++ni) {
        const int col = (ni<<4) + r15;
        const int ch = col >> 3;
        const int chs = (ch & 24) | ((ch ^ (row & 7)) & 7);
        Ps[(row<<8) + (chs<<3) + (col&7)] = f2bf(acc[mi][ni][r]*inv);
      }
    }
  }
  __syncthreads();

  f32x4 o[2][4];
#pragma unroll
  for (int mi=0;mi<2;mi++)
#pragma unroll
    for (int ni=0;ni<4;ni++)
#pragma unroll
      for (int r=0;r<4;r++) o[mi][ni][r] = 0.f;

#pragma unroll
  for (int kk=0; kk<8; ++kk) {
    bf16x8 pa[2];
#pragma unroll
    for (int mi=0; mi<2; ++mi) {
      const int row = (wid<<5) + (mi<<4) + r15;
      const int ch = (kk<<2) + q;
      const int chs = (ch & 24) | ((ch ^ (row & 7)) & 7);
      pa[mi] = *(const bf16x8*)(Ps + (row<<8) + (chs<<3));
    }
#pragma unroll
    for (int ni=0; ni<4; ++ni) {
      const int vrow = (ni<<4) + r15;
      const int ch = (kk<<2) + q;
      const int chs = (ch & 24) | ((ch ^ (vrow & 7)) & 7);
      const bf16x8 bv = *(const bf16x8*)(Vs + (vrow<<8) + (chs<<3));
      o[0][ni] = __builtin_amdgcn_mfma_f32_16x16x32_bf16(pa[0], bv, o[0][ni], 0,0,0);
      o[1][ni] = __builtin_amdgcn_mfma_f32_16x16x32_bf16(pa[1], bv, o[1][ni], 0,0,0);
    }
  }
#pragma unroll
  for (int mi=0; mi<2; ++mi)
#pragma unroll
    for (int ni=0; ni<4; ++ni)
#pragma unroll
      for (int r=0; r<4; ++r) {
        const long long m = mBase + (wid<<5) + (mi<<4) + (q<<2) + r;
        ao[m*512 + (h<<6) + (ni<<4) + r15] = f2bf(o[mi][ni][r]);
      }
}

// ---------------- double layernorm (wave-per-row) + column-sum partials + scp zero --------
__global__ __launch_bounds__(256) void ln64_k(
    const unsigned short* __restrict__ attno, const unsigned short* __restrict__ feat,
    const float* __restrict__ g1, const float* __restrict__ b1,
    const float* __restrict__ g2, const float* __restrict__ b2,
    unsigned short* __restrict__ att, float* __restrict__ colp, float* __restrict__ scp)
{
  __shared__ float cred[4][512];
  const int tid = threadIdx.x, lane = tid & 63, wid = tid >> 6;
  const int c0 = lane << 3;
  scp[((long long)blockIdx.x<<8) + tid] = 0.f;
  float g1v[8], b1v[8], g2v[8], b2v[8];
#pragma unroll
  for (int j=0;j<8;j++){ g1v[j]=g1[c0+j]; b1v[j]=b1[c0+j]; g2v[j]=g2[c0+j]; b2v[j]=b2[c0+j]; }
  float cacc[8];
#pragma unroll
  for (int j=0;j<8;j++) cacc[j]=0.f;
  for (int rr=0; rr<16; ++rr) {
    const long long row = ((long long)blockIdx.x<<6) + (rr<<2) + wid;
    const bf16x8 a = *(const bf16x8*)(attno + (row<<9) + c0);
    const bf16x8 f = *(const bf16x8*)(feat  + (row<<9) + c0);
    float xv[8]; float s=0.f, qs=0.f;
#pragma unroll
    for (int j=0;j<8;j++){ xv[j] = bf2f((unsigned short)a[j]) + bf2f((unsigned short)f[j]); s += xv[j]; qs += xv[j]*xv[j]; }
#pragma unroll
    for (int o=32;o;o>>=1){ s += __shfl_xor(s,o,64); qs += __shfl_xor(qs,o,64); }
    float m = s*(1.f/512.f);
    float rs = rsqrtf(qs*(1.f/512.f) - m*m + 1e-5f);
    float y[8]; s=0.f; qs=0.f;
#pragma unroll
    for (int j=0;j<8;j++){ y[j] = (xv[j]-m)*rs*g1v[j] + b1v[j]; s += y[j]; qs += y[j]*y[j]; }
#pragma unroll
    for (int o=32;o;o>>=1){ s += __shfl_xor(s,o,64); qs += __shfl_xor(qs,o,64); }
    m = s*(1.f/512.f);
    rs = rsqrtf(qs*(1.f/512.f) - m*m + 1e-5f);
    bf16x8 ov;
#pragma unroll
    for (int j=0;j<8;j++){ const float z = (y[j]-m)*rs*g2v[j] + b2v[j]; cacc[j] += z; ov[j] = (short)f2bf(z); }
    *(bf16x8*)(att + (row<<9) + c0) = ov;
  }
#pragma unroll
  for (int j=0;j<8;j++) cred[wid][c0+j] = cacc[j];
  __syncthreads();
  {
    const float v0 = cred[0][tid]+cred[1][tid]+cred[2][tid]+cred[3][tid];
    const float v1 = cred[0][tid+256]+cred[1][tid+256]+cred[2][tid+256]+cred[3][tid+256];
    colp[((long long)blockIdx.x<<9)+tid]     = v0;
    colp[((long long)blockIdx.x<<9)+tid+256] = v1;
  }
}

// ---------------- gates / moe stats / bag / classifier ----------------
__global__ __launch_bounds__(512) void meangates_k(const float* __restrict__ part,
    const float* __restrict__ gw, const float* __restrict__ gb, float* __restrict__ gates)
{
  __shared__ float mv[512];
  __shared__ float tmp[4];
  const int t = threadIdx.x;
  float s = 0.f;
  for (int b=0;b<256;b++) s += part[(b<<9)+t];
  mv[t] = s * (1.f/16384.f);
  __syncthreads();
  if (t < 4) {
    float a = gb[t];
    for (int d=0; d<512; ++d) a += mv[d]*gw[d*4+t];
    tmp[t] = a;
  }
  __syncthreads();
  if (t == 0) {
    const float m = fmaxf(fmaxf(tmp[0],tmp[1]),fmaxf(tmp[2],tmp[3]));
    float e[4]; float ss=0.f;
    for (int i=0;i<4;i++){ e[i]=__expf(tmp[i]-m); ss+=e[i]; }
    for (int i=0;i<4;i++) gates[i] = e[i]/ss;
  }
}

__global__ __launch_bounds__(1024) void moestat_k(const float* __restrict__ sc,
                                                  float* __restrict__ mstat, float* __restrict__ sstat)
{
  __shared__ float red[1024];
  const int e = blockIdx.x, t = threadIdx.x;
  const float* p = sc + e*16384;
  float m = -3.4e38f;
  for (int n=t; n<16384; n+=1024) m = fmaxf(m, p[n]);
  red[t] = m; __syncthreads();
  for (int o=512;o;o>>=1){ if (t<o) red[t]=fmaxf(red[t],red[t+o]); __syncthreads(); }
  m = red[0]; __syncthreads();
  float s = 0.f;
  for (int n=t; n<16384; n+=1024) s += __expf(p[n]-m);
  red[t] = s; __syncthreads();
  for (int o=512;o;o>>=1){ if (t<o) red[t]+=red[t+o]; __syncthreads(); }
  if (t==0){ mstat[e]=m; sstat[e]=red[0]; }
}

__global__ __launch_bounds__(256) void wbag_k(const unsigned short* __restrict__ att,
    const float* __restrict__ scp, const float* __restrict__ gates,
    const float* __restrict__ mstat, const float* __restrict__ sstat,
    float* __restrict__ part, float* __restrict__ dout)
{
  __shared__ float wrow[128];
  const int c = threadIdx.x;
  const long long r0 = (long long)blockIdx.x * 128;
  if (c < 128) {
    const long long n = r0 + c;
    float w = 0.f;
#pragma unroll
    for (int e=0;e<4;e++) w += gates[e]*__expf(scp[((long long)e<<14)+n]-mstat[e]) / sstat[e];
    wrow[c] = w;
    dout[514 + n] = w;
  }
  __syncthreads();
  float a0=0.f, a1=0.f;
  for (int r=0;r<128;r++){
    const float w = wrow[r];
    const unsigned short* p = att + ((r0+r)<<9);
    a0 += w*bf2f(p[c]); a1 += w*bf2f(p[c+256]);
  }
  part[((long long)blockIdx.x<<9)+c]     = a0;
  part[((long long)blockIdx.x<<9)+c+256] = a1;
}

__global__ __launch_bounds__(512) void cls2_k(const float* __restrict__ bagp,
    const float* __restrict__ w1, const float* __restrict__ b1,
    const float* __restrict__ w2, const float* __restrict__ b2,
    const float* __restrict__ w3, const float* __restrict__ b3, float* __restrict__ dout)
{
  __shared__ float bag[512]; __shared__ float c1[256]; __shared__ float c2[128];
  const int tid = threadIdx.x;
  float s = 0.f;
  for (int b=0;b<128;b++) s += bagp[(b<<9)+tid];
  bag[tid] = s; dout[tid] = s;
  __syncthreads();
  if (tid < 256) {
    float a = b1[tid];
    for (int d=0; d<512; ++d) a += bag[d]*w1[d*256+tid];
    c1[tid] = fmaxf(a, 0.f);
  }
  __syncthreads();
  if (tid < 128) {
    float a2 = b2[tid];
    for (int d=0; d<256; ++d) a2 += c1[d]*w2[d*128+tid];
    c2[tid] = fmaxf(a2, 0.f);
  }
  __syncthreads();
  if (tid < 2) {
    float a3 = b3[tid];
    for (int d=0; d<128; ++d) a3 += c2[d]*w3[d*2+tid];
    dout[512 + tid] = a3;
  }
}

extern "C" void kernel_launch(void* const* d_in, const int* in_sizes, int n_in,
                              void* d_out, int out_size, void* d_ws, size_t ws_size,
                              hipStream_t stream)
{
  (void)in_sizes; (void)n_in; (void)out_size; (void)ws_size;
  const float* x      = (const float*)d_in[0];
  const float* enc_w1 = (const float*)d_in[1];
  const float* enc_b1 = (const float*)d_in[2];
  const float* enc_w2 = (const float*)d_in[3];
  const float* enc_b2 = (const float*)d_in[4];
  const float* enc_w3 = (const float*)d_in[5];
  const float* enc_b3 = (const float*)d_in[6];
  const float* q_w    = (const float*)d_in[7];
  const float* q_b    = (const float*)d_in[8];
  const float* k_w    = (const float*)d_in[9];
  const float* k_b    = (const float*)d_in[10];
  const float* v_w    = (const float*)d_in[11];
  const float* v_b    = (const float*)d_in[12];
  const float* o_w    = (const float*)d_in[13];
  const float* o_b    = (const float*)d_in[14];
  const float* E_w    = (const float*)d_in[15];
  const float* F_w    = (const float*)d_in[16];
  const float* ln1_g  = (const float*)d_in[17];
  const float* ln1_b  = (const float*)d_in[18];
  const float* ln2_g  = (const float*)d_in[19];
  const float* ln2_b  = (const float*)d_in[20];
  const float* gate_w = (const float*)d_in[21];
  const float* gate_b = (const float*)d_in[22];
  const float* moe_w1 = (const float*)d_in[23];
  const float* moe_b1 = (const float*)d_in[24];
  const float* moe_w2 = (const float*)d_in[25];
  // d_in[26] = moe_b2: drops out of the row-softmax (shift invariance)
  const float* cls_w1 = (const float*)d_in[27];
  const float* cls_b1 = (const float*)d_in[28];
  const float* cls_w2 = (const float*)d_in[29];
  const float* cls_b2 = (const float*)d_in[30];
  const float* cls_w3 = (const float*)d_in[31];
  const float* cls_b3 = (const float*)d_in[32];

  char* ws = (char*)d_ws;
  const size_t MB = 1024*1024;
  unsigned short* h1    = (unsigned short*)(ws + 64*MB);      // [16384][1024]  32MB
  unsigned short* h2    = (unsigned short*)(ws + 0);          // 16MB
  unsigned short* feat  = (unsigned short*)(ws + 16*MB);      // 16MB
  unsigned short* qkv   = (unsigned short*)(ws + 32*MB);      // [16384][1536]  48MB (h1 dead)
  unsigned short* ao    = (unsigned short*)(ws + 80*MB);      // 16MB
  unsigned short* attno = (unsigned short*)(ws + 0);          // 16MB (h2 dead)
  unsigned short* att   = (unsigned short*)(ws + 96*MB);      // 16MB
  unsigned short* w1t   = (unsigned short*)(ws + 112*MB);                 // [1024][2048] 4MB
  unsigned short* w2t   = (unsigned short*)(ws + 116*MB);                 // 1MB
  unsigned short* w3t   = (unsigned short*)(ws + 117*MB);                 // 0.5MB
  unsigned short* qkvw  = (unsigned short*)(ws + 117*MB + 512*1024);      // 1.5MB
  unsigned short* owt   = (unsigned short*)(ws + 119*MB);                 // 0.5MB
  unsigned short* mwt   = (unsigned short*)(ws + 119*MB + 512*1024);      // 1MB
  float*  t1b   = (float*)(ws + 120*MB + 512*1024);                       // 0.5MB
  float*  redb  = (float*)(ws + 121*MB);                                  // 1MB
  unsigned short* Kcbf  = (unsigned short*)(ws + 122*MB);                 // 256KB
  unsigned short* Vctbf = (unsigned short*)(ws + 122*MB + 256*1024);      // 256KB
  float*  colp  = (float*)(ws + 122*MB + 512*1024);                       // [256][512] 512KB
  float*  bagp  = (float*)(ws + 123*MB);                                  // [128][512] 256KB
  float*  qkvb  = (float*)(ws + 123*MB + 256*1024);                       // 6KB
  float*  gatesp= (float*)(ws + 123*MB + 264*1024);
  float*  scp   = (float*)(ws + 123*MB + 268*1024);                       // [4][16384] 256KB
  float*  mstat = (float*)(ws + 123*MB + 524*1024);
  float*  sstat = (float*)(ws + 123*MB + 524*1024 + 64);
  float*  dout  = (float*)d_out;

  // ---- prep (t1 + weight transposes + qkvb); x is consumed directly by gemm6 ----
  prep_k<<<1601,256,0,stream>>>(enc_w1, w1t, enc_w2, w2t,
                                enc_w3, q_w, k_w, v_w, o_w, w3t, qkvw, owt,
                                moe_w1, mwt, E_w, F_w, t1b, q_b, k_b, v_b, qkvb);

  // ---- encoder (enc1 fuses f32->bf16 conversion of x) ----
  gemm6_k<1><<<dim3(4,64,1),512,0,stream>>>(x, w1t, enc_b1, h1, 2000,2048,1024);
  gemm5_k<1><<<dim3(4,128,1),256,0,stream>>>(h1, w2t, enc_b2, h2,   1024,1024,1024, 512);
  gemm5_k<1><<<dim3(4,128,1),256,0,stream>>>(h2, w3t, enc_b3, feat,  512, 512, 512, 512);
  // ---- QKV (merged, N=1536) ----
  gemm5_k<0><<<dim3(12,128,1),256,0,stream>>>(feat, qkvw, qkvb, qkv, 512,512,512,1536);
  // ---- linformer projections ----
  red_k<<<dim3(256,2),512,0,stream>>>(qkv, redb);
  kc_k <<<dim3(256,2),512,0,stream>>>(t1b, redb, Kcbf, Vctbf);
  // ---- fused attention ----
  attn_k<<<dim3(128,8),256,0,stream>>>(qkv, Kcbf, Vctbf, ao);
  // ---- output projection + residual + double LN (+ colsum partials + scp zero) ----
  gemm5_k<0><<<dim3(4,128,1),256,0,stream>>>(ao, owt, o_b, attno, 512,512,512,512);
  ln64_k<<<256,256,0,stream>>>(attno, feat, ln1_g, ln1_b, ln2_g, ln2_b, att, colp, scp);
  meangates_k<<<1,512,0,stream>>>(colp, gate_w, gate_b, gatesp);
  // ---- MoE expert attention: ONE merged N=1024 GEMM, tanh+dot fused in epilogue ----
  gemm4_k<0,true><<<dim3(4,64,1),512,0,stream>>>(att, mwt, moe_b1, nullptr, moe_w2, scp, 512,512,512,0);
  moestat_k<<<4,1024,0,stream>>>(scp, mstat, sstat);
  // ---- attn weights + bag partials (fused) + classifier ----
  wbag_k<<<128,256,0,stream>>>(att, scp, gatesp, mstat, sstat, bagp, dout);
  cls2_k<<<1,512,0,stream>>>(bagp, cls_w1, cls_b1, cls_w2, cls_b2, cls_w3, cls_b3, dout);
}

// Round 12
// 432.560 us; speedup vs baseline: 1.1172x; 1.1172x over previous
//
#include <hip/hip_runtime.h>

#define DI __device__ __forceinline__

DI float bf2f(unsigned short u){ unsigned int v = ((unsigned int)u)<<16; float f; __builtin_memcpy(&f,&v,4); return f; }
DI unsigned short f2bf(float f){ unsigned int v; __builtin_memcpy(&v,&f,4); v = v + 0x7FFFu + ((v>>16)&1u); return (unsigned short)(v>>16); }

typedef __attribute__((ext_vector_type(8))) short bf16x8;
typedef __attribute__((ext_vector_type(4))) short short4v;
typedef __attribute__((ext_vector_type(4))) float f32x4;

#define GLD_LDS16(src, dst) __builtin_amdgcn_global_load_lds( \
    (const __attribute__((address_space(1))) void*)(src), \
    (__attribute__((address_space(3))) void*)(dst), 16, 0, 0)

DI void barrier_() { asm volatile("" ::: "memory"); __builtin_amdgcn_s_barrier(); asm volatile("" ::: "memory"); }

// ---------------- gemm5: 128x128 tile, 4-phase counted-vmcnt pipeline ----------------
template<int ACT>
__global__ __launch_bounds__(256,2) void gemm5_k(
    const unsigned short* __restrict__ A, const unsigned short* __restrict__ Bt,
    const float* __restrict__ bias, unsigned short* __restrict__ C,
    int K, int lda, int ldb, int ldc)
{
  __shared__ unsigned short As[2][8192];
  __shared__ unsigned short Bs[2][8192];
  const int tid = threadIdx.x, lane = tid & 63, wid = tid >> 6;
  const int wm = wid >> 1, wn = wid & 1;
  const int q = lane >> 4, r15 = lane & 15;
  const int nx = gridDim.x;
  const int bid = blockIdx.x + nx*blockIdx.y;
  const int cpx = (nx*gridDim.y) >> 3;
  const int wg = (bid & 7)*cpx + (bid >> 3);
  const long long mBase = (long long)(wg / nx) << 7;
  const long long nBase = (long long)(wg % nx) << 7;

  f32x4 acc[4][4];
#pragma unroll
  for (int i=0;i<4;i++)
#pragma unroll
    for (int j=0;j<4;j++)
#pragma unroll
      for (int r=0;r<4;r++) acc[i][j][r] = 0.f;

  const int NT = K >> 6;

#define G5_STA(j, nb, kk) { const int d_ = tid + ((j)<<8); const int row_ = d_>>3, c_ = d_&7, sc_ = c_ ^ (row_&7); \
    GLD_LDS16(A + (mBase+row_)*(long long)lda + (kk) + (sc_<<3), &As[nb][d_<<3]); }
#define G5_STB(j, nb, kk) { const int d_ = tid + ((j)<<8); const int row_ = d_>>3, c_ = d_&7, sc_ = c_ ^ (row_&7); \
    GLD_LDS16(Bt + (nBase+row_)*(long long)ldb + (kk) + (sc_<<3), &Bs[nb][d_<<3]); }

  G5_STB(0,0,0); G5_STB(2,0,0); G5_STB(1,0,0); G5_STB(3,0,0);
  G5_STA(0,0,0); G5_STA(2,0,0); G5_STA(1,0,0); G5_STA(3,0,0);

  for (int t=0; t<NT; ++t) {
    const int b = t & 1, nb = b ^ 1;
    const bool more = (t+1 < NT);
    const int k1 = (t+1) << 6;
    bf16x8 aL[4], aH[4], bL[4], bH[4];

    asm volatile("s_waitcnt vmcnt(2)" ::: "memory");
    barrier_();
#pragma unroll
    for (int mi=0; mi<2; ++mi)
#pragma unroll
      for (int ks=0; ks<2; ++ks) {
        const int row = (wm<<6) + (mi<<4) + r15;
        const int ch = ((ks<<2)+q) ^ (row&7);
        aL[mi*2+ks] = *(const bf16x8*)&As[b][(row<<6) + (ch<<3)];
      }
#pragma unroll
    for (int ni=0; ni<2; ++ni)
#pragma unroll
      for (int ks=0; ks<2; ++ks) {
        const int col = (wn<<6) + (ni<<4) + r15;
        const int ch = ((ks<<2)+q) ^ (col&7);
        bL[ni*2+ks] = *(const bf16x8*)&Bs[b][(col<<6) + (ch<<3)];
      }
    if (more) { G5_STB(0,nb,k1); G5_STB(2,nb,k1); }
    __builtin_amdgcn_s_setprio(1);
#pragma unroll
    for (int mi=0; mi<2; ++mi)
#pragma unroll
      for (int ni=0; ni<2; ++ni)
#pragma unroll
        for (int ks=0; ks<2; ++ks)
          acc[mi][ni] = __builtin_amdgcn_mfma_f32_16x16x32_bf16(aL[mi*2+ks], bL[ni*2+ks], acc[mi][ni], 0,0,0);
    __builtin_amdgcn_s_setprio(0);
    barrier_();

#pragma unroll
    for (int ni=0; ni<2; ++ni)
#pragma unroll
      for (int ks=0; ks<2; ++ks) {
        const int col = (wn<<6) + ((ni+2)<<4) + r15;
        const int ch = ((ks<<2)+q) ^ (col&7);
        bH[ni*2+ks] = *(const bf16x8*)&Bs[b][(col<<6) + (ch<<3)];
      }
    if (more) { G5_STB(1,nb,k1); G5_STB(3,nb,k1); }
    __builtin_amdgcn_s_setprio(1);
#pragma unroll
    for (int mi=0; mi<2; ++mi)
#pragma unroll
      for (int ni=0; ni<2; ++ni)
#pragma unroll
        for (int ks=0; ks<2; ++ks)
          acc[mi][ni+2] = __builtin_amdgcn_mfma_f32_16x16x32_bf16(aL[mi*2+ks], bH[ni*2+ks], acc[mi][ni+2], 0,0,0);
    __builtin_amdgcn_s_setprio(0);

    if (more) { asm volatile("s_waitcnt vmcnt(4)" ::: "memory"); }
    else      { asm volatile("s_waitcnt vmcnt(0)" ::: "memory"); }
    barrier_();
#pragma unroll
    for (int mi=0; mi<2; ++mi)
#pragma unroll
      for (int ks=0; ks<2; ++ks) {
        const int row = (wm<<6) + ((mi+2)<<4) + r15;
        const int ch = ((ks<<2)+q) ^ (row&7);
        aH[mi*2+ks] = *(const bf16x8*)&As[b][(row<<6) + (ch<<3)];
      }
    if (more) { G5_STA(0,nb,k1); G5_STA(2,nb,k1); }
    __builtin_amdgcn_s_setprio(1);
#pragma unroll
    for (int mi=0; mi<2; ++mi)
#pragma unroll
      for (int ni=0; ni<2; ++ni)
#pragma unroll
        for (int ks=0; ks<2; ++ks)
          acc[mi+2][ni] = __builtin_amdgcn_mfma_f32_16x16x32_bf16(aH[mi*2+ks], bL[ni*2+ks], acc[mi+2][ni], 0,0,0);
    __builtin_amdgcn_s_setprio(0);
    barrier_();

    if (more) { G5_STA(1,nb,k1); G5_STA(3,nb,k1); }
    __builtin_amdgcn_s_setprio(1);
#pragma unroll
    for (int mi=0; mi<2; ++mi)
#pragma unroll
      for (int ni=0; ni<2; ++ni)
#pragma unroll
        for (int ks=0; ks<2; ++ks)
          acc[mi+2][ni+2] = __builtin_amdgcn_mfma_f32_16x16x32_bf16(aH[mi*2+ks], bH[ni*2+ks], acc[mi+2][ni+2], 0,0,0);
    __builtin_amdgcn_s_setprio(0);
  }
#undef G5_STA
#undef G5_STB

#pragma unroll
  for (int ni=0; ni<4; ++ni) {
    const long long n = nBase + (wn<<6) + (ni<<4) + r15;
    const float bval = bias[n];
#pragma unroll
    for (int mi=0; mi<4; ++mi) {
#pragma unroll
      for (int r=0; r<4; ++r) {
        const long long m = mBase + (wm<<6) + (mi<<4) + (q<<2) + r;
        float v = acc[mi][ni][r] + bval;
        if constexpr (ACT==1) v = fmaxf(v, 0.f);
        C[m*(long long)ldc + n] = f2bf(v);
      }
    }
  }
}

// ---------------- gemm4: 256x256 tile, 4-phase counted-vmcnt pipeline ----------------
template<int ACT, bool MOE>
__global__ __launch_bounds__(512,2) void gemm4_k(
    const unsigned short* __restrict__ A, const unsigned short* __restrict__ Bt,
    const float* __restrict__ bias, unsigned short* __restrict__ C,
    const float* __restrict__ w2, float* __restrict__ scp,
    int K, int lda, int ldb, int ldc)
{
  __shared__ unsigned short As[2][16384];
  __shared__ unsigned short Bs[2][16384];
  const int tid = threadIdx.x, lane = tid & 63, wid = tid >> 6;
  const int wm = wid >> 2, wn = wid & 3;
  const int q = lane >> 4, r15 = lane & 15;
  const int nx = gridDim.x;
  const int bid = blockIdx.x + nx*blockIdx.y;
  const int cpx = (nx*gridDim.y) >> 3;
  const int wg = (bid & 7)*cpx + (bid >> 3);
  const long long mBase = (long long)(wg / nx) << 8;
  const long long nBase = (long long)(wg % nx) << 8;

  f32x4 acc[8][4];
#pragma unroll
  for (int i=0;i<8;i++)
#pragma unroll
    for (int j=0;j<4;j++)
#pragma unroll
      for (int r=0;r<4;r++) acc[i][j][r] = 0.f;

  const int NT = K >> 6;

#define G4_STA(j, nb, kk) { const int d_ = tid + ((j)<<9); const int row_ = d_>>3, c_ = d_&7, sc_ = c_ ^ (row_&7); \
    GLD_LDS16(A + (mBase+row_)*(long long)lda + (kk) + (sc_<<3), &As[nb][d_<<3]); }
#define G4_STB(j, nb, kk) { const int d_ = tid + ((j)<<9); const int row_ = d_>>3, c_ = d_&7, sc_ = c_ ^ (row_&7); \
    GLD_LDS16(Bt + (nBase+row_)*(long long)ldb + (kk) + (sc_<<3), &Bs[nb][d_<<3]); }

  G4_STB(0,0,0); G4_STB(1,0,0); G4_STB(2,0,0); G4_STB(3,0,0);
  G4_STA(0,0,0); G4_STA(2,0,0); G4_STA(1,0,0); G4_STA(3,0,0);

  for (int t=0; t<NT; ++t) {
    const int b = t & 1, nb = b ^ 1;
    const bool more = (t+1 < NT);
    const int k1 = (t+1) << 6;
    bf16x8 aF[8], bL[4], bH[4];

    asm volatile("s_waitcnt vmcnt(2)" ::: "memory");
    barrier_();
#pragma unroll
    for (int mi=0; mi<4; ++mi)
#pragma unroll
      for (int ks=0; ks<2; ++ks) {
        const int row = (wm<<7) + (mi<<4) + r15;
        const int ch = ((ks<<2)+q) ^ (row&7);
        aF[mi*2+ks] = *(const bf16x8*)&As[b][(row<<6) + (ch<<3)];
      }
#pragma unroll
    for (int ni=0; ni<2; ++ni)
#pragma unroll
      for (int ks=0; ks<2; ++ks) {
        const int col = (wn<<6) + (ni<<4) + r15;
        const int ch = ((ks<<2)+q) ^ (col&7);
        bL[ni*2+ks] = *(const bf16x8*)&Bs[b][(col<<6) + (ch<<3)];
      }
    if (more) { G4_STB(0,nb,k1); G4_STB(1,nb,k1); }
    __builtin_amdgcn_s_setprio(1);
#pragma unroll
    for (int mi=0; mi<4; ++mi)
#pragma unroll
      for (int ni=0; ni<2; ++ni)
#pragma unroll
        for (int ks=0; ks<2; ++ks)
          acc[mi][ni] = __builtin_amdgcn_mfma_f32_16x16x32_bf16(aF[mi*2+ks], bL[ni*2+ks], acc[mi][ni], 0,0,0);
    __builtin_amdgcn_s_setprio(0);
    barrier_();

#pragma unroll
    for (int ni=0; ni<2; ++ni)
#pragma unroll
      for (int ks=0; ks<2; ++ks) {
        const int col = (wn<<6) + ((ni+2)<<4) + r15;
        const int ch = ((ks<<2)+q) ^ (col&7);
        bH[ni*2+ks] = *(const bf16x8*)&Bs[b][(col<<6) + (ch<<3)];
      }
    if (more) { G4_STB(2,nb,k1); G4_STB(3,nb,k1); }
    __builtin_amdgcn_s_setprio(1);
#pragma unroll
    for (int mi=0; mi<4; ++mi)
#pragma unroll
      for (int ni=0; ni<2; ++ni)
#pragma unroll
        for (int ks=0; ks<2; ++ks)
          acc[mi][ni+2] = __builtin_amdgcn_mfma_f32_16x16x32_bf16(aF[mi*2+ks], bH[ni*2+ks], acc[mi][ni+2], 0,0,0);
    __builtin_amdgcn_s_setprio(0);

    if (more) { asm volatile("s_waitcnt vmcnt(4)" ::: "memory"); }
    else      { asm volatile("s_waitcnt vmcnt(0)" ::: "memory"); }
    barrier_();
#pragma unroll
    for (int mi=0; mi<4; ++mi)
#pragma unroll
      for (int ks=0; ks<2; ++ks) {
        const int row = (wm<<7) + ((mi+4)<<4) + r15;
        const int ch = ((ks<<2)+q) ^ (row&7);
        aF[mi*2+ks] = *(const bf16x8*)&As[b][(row<<6) + (ch<<3)];
      }
    if (more) { G4_STA(0,nb,k1); G4_STA(2,nb,k1); }
    __builtin_amdgcn_s_setprio(1);
#pragma unroll
    for (int mi=0; mi<4; ++mi)
#pragma unroll
      for (int ni=0; ni<2; ++ni)
#pragma unroll
        for (int ks=0; ks<2; ++ks)
          acc[mi+4][ni] = __builtin_amdgcn_mfma_f32_16x16x32_bf16(aF[mi*2+ks], bL[ni*2+ks], acc[mi+4][ni], 0,0,0);
    __builtin_amdgcn_s_setprio(0);
    barrier_();

    if (more) { G4_STA(1,nb,k1); G4_STA(3,nb,k1); }
    __builtin_amdgcn_s_setprio(1);
#pragma unroll
    for (int mi=0; mi<4; ++mi)
#pragma unroll
      for (int ni=0; ni<2; ++ni)
#pragma unroll
        for (int ks=0; ks<2; ++ks)
          acc[mi+4][ni+2] = __builtin_amdgcn_mfma_f32_16x16x32_bf16(aF[mi*2+ks], bH[ni*2+ks], acc[mi+4][ni+2], 0,0,0);
    __builtin_amdgcn_s_setprio(0);
  }
#undef G4_STA
#undef G4_STB

  if constexpr (MOE) {
    const int e = (int)(nBase >> 8);
#pragma unroll
    for (int mi=0; mi<8; ++mi) {
#pragma unroll
      for (int r=0; r<4; ++r) {
        float p = 0.f;
#pragma unroll
        for (int ni=0; ni<4; ++ni) {
          const int n = (int)nBase + (wn<<6) + (ni<<4) + r15;
          const float v = acc[mi][ni][r] + bias[n];
          const float th = 1.f - 2.f/(__expf(2.f*v) + 1.f);
          p += th * w2[n];
        }
        p += __shfl_xor(p,1,64); p += __shfl_xor(p,2,64);
        p += __shfl_xor(p,4,64); p += __shfl_xor(p,8,64);
        if (r15 == 0) {
          const long long m = mBase + (wm<<7) + (mi<<4) + (q<<2) + r;
          atomicAdd(scp + ((long long)e<<14) + m, p);
        }
      }
    }
  } else {
#pragma unroll
    for (int ni=0; ni<4; ++ni) {
      const long long n = nBase + (wn<<6) + (ni<<4) + r15;
      const float bval = bias[n];
#pragma unroll
      for (int mi=0; mi<8; ++mi) {
#pragma unroll
        for (int r=0; r<4; ++r) {
          const long long m = mBase + (wm<<7) + (mi<<4) + (q<<2) + r;
          float v = acc[mi][ni][r] + bval;
          if constexpr (ACT==1) v = fmaxf(v, 0.f);
          C[m*(long long)ldc + n] = f2bf(v);
        }
      }
    }
  }
}

// ---------------- mega prep ----------------
DI void transpose64(const float* __restrict__ src, unsigned short* __restrict__ dst,
                    int K, int N, int Kpad, int k0, int n0, float (*tile)[65], int tid)
{
  const int c = tid & 63, rg = tid >> 6;
#pragma unroll
  for (int j=0;j<16;j++){
    const int r = (j<<2) + rg;
    const int k = k0 + r;
    tile[r][c] = (k < K) ? src[(long long)k*N + n0 + c] : 0.f;
  }
  __syncthreads();
#pragma unroll
  for (int j=0;j<16;j++){
    const int nn = (j<<2) + rg;
    dst[(long long)(n0+nn)*Kpad + k0 + c] = f2bf(tile[c][nn]);
  }
}

__global__ __launch_bounds__(256) void prep_k(
    const float* __restrict__ x, unsigned short* __restrict__ xb,
    const float* __restrict__ enc_w1, unsigned short* __restrict__ w1t,
    const float* __restrict__ enc_w2, unsigned short* __restrict__ w2t,
    const float* __restrict__ enc_w3, const float* __restrict__ q_w,
    const float* __restrict__ k_w, const float* __restrict__ v_w, const float* __restrict__ o_w,
    unsigned short* __restrict__ w3t, unsigned short* __restrict__ qkvw, unsigned short* __restrict__ owt,
    const float* __restrict__ moe_w1, unsigned short* __restrict__ mwt,
    const float* __restrict__ Ew, const float* __restrict__ Fw, float* __restrict__ t1,
    const float* __restrict__ qb, const float* __restrict__ kb, const float* __restrict__ vb,
    float* __restrict__ qkvb)
{
  __shared__ float tile[64][65];
  const int b = blockIdx.x, tid = threadIdx.x;
  if (b < 512) {
    // t1 band reduction (8-wide unroll; band data L2-resident after first k)
    const int k = b & 255, which = b >> 8, c = tid;
    const float* Wr = (which ? Fw : Ew) + (long long)c*10000;
    const float ksc = 39.0625f, inv = 1.f/39.0625f;
    const float sf = (k + 0.5f)*ksc - 0.5f;
    int ilo = (int)ceilf(sf - ksc); if (ilo < 0) ilo = 0;
    int ihi = (int)floorf(sf + ksc); if (ihi > 9999) ihi = 9999;
    float acc = 0.f, wsum = 0.f;
    int i = ilo;
    for (; i + 8 <= ihi + 1; i += 8) {
      float v[8];
#pragma unroll
      for (int j=0;j<8;j++) v[j] = Wr[i+j];
#pragma unroll
      for (int j=0;j<8;j++){
        const float w = fmaxf(1.f - fabsf(sf - (float)(i+j))*inv, 0.f);
        acc += w*v[j]; wsum += w;
      }
    }
    for (; i <= ihi; ++i) {
      const float w = fmaxf(1.f - fabsf(sf - (float)i)*inv, 0.f);
      acc += w * Wr[i]; wsum += w;
    }
    t1[(which*256 + k)*256 + c] = acc / wsum;
  } else if (b < 1024) {
    const int bb = b - 512;
    transpose64(enc_w1, w1t, 2000, 1024, 2048, (bb&31)<<6, (bb>>5)<<6, tile, tid);
  } else if (b < 1152) {
    const int bb = b - 1024;
    transpose64(enc_w2, w2t, 1024, 512, 1024, (bb&15)<<6, (bb>>4)<<6, tile, tid);
  } else if (b < 1472) {
    const int bb = b - 1152;
    const int z = bb >> 6, r = bb & 63;
    const float* s = (z==0)?enc_w3:(z==1)?q_w:(z==2)?k_w:(z==3)?v_w:o_w;
    unsigned short* d = (z==0)?w3t:(z==1)?qkvw:(z==2)?(qkvw+512*512):(z==3)?(qkvw+1024*512):owt;
    transpose64(s, d, 512, 512, 512, (r&7)<<6, (r>>3)<<6, tile, tid);
  } else if (b < 1600) {
    const int bb = b - 1472;
    const int z = bb >> 5, r = bb & 31;
    transpose64(moe_w1 + (long long)z*512*256, mwt + (long long)z*256*512,
                512, 256, 512, (r&7)<<6, (r>>3)<<6, tile, tid);
  } else if (b == 1600) {
#pragma unroll
    for (int i=0;i<6;i++){
      const int idx = i*256 + tid;
      const int wq = idx >> 9, off = idx & 511;
      const float* src = (wq==0)?qb:(wq==1)?kb:vb;
      qkvb[idx] = src[off];
    }
  } else if (b < 1985) {
    // zero the pad region xb[:, 2000:2048] (384 blocks x 256 chunks of 8 bf16)
    const int p = (b - 1601)*256 + tid;          // 0..98303
    const int row = p / 6, cc = p - row*6;
    bf16x8 z8;
#pragma unroll
    for (int j=0;j<8;j++) z8[j]=0;
    *(bf16x8*)(xb + (long long)row*2048 + 2000 + cc*8) = z8;
  } else {
    // x flat convert: lane-CONTIGUOUS float4 loads (16B/lane per instruction)
    const int bb = b - 1985;                     // 0..2047
    const long long base = (long long)bb*256 + tid;
#pragma unroll
    for (int j=0;j<16;j++){
      const long long id = base + (long long)j*524288;
      if (id < 8192000) {
        const float4 f = *((const float4*)x + id);
        const long long row = id / 500;
        const int col = (int)(id - row*500);
        short4v o;
        o[0]=(short)f2bf(f.x); o[1]=(short)f2bf(f.y); o[2]=(short)f2bf(f.z); o[3]=(short)f2bf(f.w);
        *(short4v*)(xb + row*2048 + (long long)col*4) = o;
      }
    }
  }
}

// ---------------- linformer projection helpers ----------------
__global__ __launch_bounds__(512) void red_k(const unsigned short* __restrict__ qkv,
                                             float* __restrict__ red)
{
  const int c = blockIdx.x, which = blockIdx.y, j = threadIdx.x;
  const unsigned short* X = qkv + (which ? 1024 : 512);
  int nlo = 64*c - 32; if (nlo < 0) nlo = 0;
  int nhi = 64*c + 95; if (nhi > 16383) nhi = 16383;
  float acc = 0.f;
  for (int n=nlo; n<=nhi; ++n) {
    float sf = (n + 0.5f)*0.015625f - 0.5f;
    sf = fminf(fmaxf(sf, 0.f), 255.f);
    const int c0 = (int)sf;
    const float f = sf - (float)c0;
    float w = 0.f;
    if (c == c0) w = 1.f - f;
    else if (c == c0+1) w = f;
    if (w != 0.f) acc += w * bf2f(X[(long long)n*1536 + j]);
  }
  red[(which*256 + c)*512 + j] = acc;
}

__global__ __launch_bounds__(512) void kc_k(const float* __restrict__ t1, const float* __restrict__ red,
                                            unsigned short* __restrict__ Kc, unsigned short* __restrict__ Vct)
{
  const int k = blockIdx.x, which = blockIdx.y, j = threadIdx.x;
  const float* T = t1 + (which*256 + k)*256;
  const float* R = red + which*131072;
  float acc = 0.f;
  for (int c=0; c<256; ++c) acc += T[c] * R[c*512 + j];
  const int h = j >> 6, d = j & 63;
  if (which == 0) Kc [(h<<14) + (k<<6) + d] = f2bf(acc);
  else            Vct[(h<<14) + (d<<8) + k] = f2bf(acc);
}

// ---------------- fused linformer attention ----------------
__global__ __launch_bounds__(256) void attn_k(
    const unsigned short* __restrict__ Qg, const unsigned short* __restrict__ Kc,
    const unsigned short* __restrict__ Vct, unsigned short* __restrict__ ao)
{
  __shared__ unsigned short Ks[16384];
  __shared__ unsigned short Vs[16384];
  __shared__ unsigned short Ps[32768];
  const int h = blockIdx.y;
  const long long mBase = (long long)blockIdx.x << 7;
  const int tid = threadIdx.x, lane = tid & 63, wid = tid >> 6;
  const int q = lane >> 4, r15 = lane & 15;

#pragma unroll
  for (int it=0; it<8; ++it) {
    const int dbase = (it<<8) + (wid<<6);
    const int d = dbase + lane;
    {
      const int row = d >> 3, cc = d & 7, sc = cc ^ (row & 7);
      GLD_LDS16(Kc + (h<<14) + (row<<6) + (sc<<3), Ks + (dbase<<3));
    }
    {
      const int row = d >> 5, cc = d & 31, sc = (cc & 24) | ((cc ^ (row & 7)) & 7);
      GLD_LDS16(Vct + (h<<14) + (row<<8) + (sc<<3), Vs + (dbase<<3));
    }
  }
  __syncthreads();

  f32x4 acc[2][16];
#pragma unroll
  for (int mi=0;mi<2;mi++)
#pragma unroll
    for (int ni=0;ni<16;ni++)
#pragma unroll
      for (int r=0;r<4;r++) acc[mi][ni][r] = 0.f;

#pragma unroll
  for (int ks=0; ks<2; ++ks) {
    bf16x8 af[2];
#pragma unroll
    for (int mi=0; mi<2; ++mi) {
      const long long m = mBase + (wid<<5) + (mi<<4) + r15;
      af[mi] = *(const bf16x8*)(Qg + m*1536 + (h<<6) + (ks<<5) + (q<<3));
    }
#pragma unroll
    for (int ni=0; ni<16; ++ni) {
      const int col = (ni<<4) + r15;
      const int ch = ((ks<<2)+q) ^ (col&7);
      const bf16x8 bv = *(const bf16x8*)(Ks + (col<<6) + (ch<<3));
      acc[0][ni] = __builtin_amdgcn_mfma_f32_16x16x32_bf16(af[0], bv, acc[0][ni], 0,0,0);
      acc[1][ni] = __builtin_amdgcn_mfma_f32_16x16x32_bf16(af[1], bv, acc[1][ni], 0,0,0);
    }
  }

#pragma unroll
  for (int mi=0; mi<2; ++mi) {
#pragma unroll
    for (int r=0; r<4; ++r) {
      float mx = -3.4e38f;
#pragma unroll
      for (int ni=0; ni<16; ++ni) mx = fmaxf(mx, acc[mi][ni][r]);
      mx = fmaxf(mx, __shfl_xor(mx,1,64)); mx = fmaxf(mx, __shfl_xor(mx,2,64));
      mx = fmaxf(mx, __shfl_xor(mx,4,64)); mx = fmaxf(mx, __shfl_xor(mx,8,64));
      float s = 0.f;
#pragma unroll
      for (int ni=0; ni<16; ++ni) {
        const float e = __expf((acc[mi][ni][r] - mx)*0.125f);
        acc[mi][ni][r] = e; s += e;
      }
      s += __shfl_xor(s,1,64); s += __shfl_xor(s,2,64);
      s += __shfl_xor(s,4,64); s += __shfl_xor(s,8,64);
      const float inv = 1.f / s;
      const int row = (wid<<5) + (mi<<4) + (q<<2) + r;
#pragma unroll
      for (int ni=0; ni<16; ++ni) {
        const int col = (ni<<4) + r15;
        const int ch = col >> 3;
        const int chs = (ch & 24) | ((ch ^ (row & 7)) & 7);
        Ps[(row<<8) + (chs<<3) + (col&7)] = f2bf(acc[mi][ni][r]*inv);
      }
    }
  }
  __syncthreads();

  f32x4 o[2][4];
#pragma unroll
  for (int mi=0;mi<2;mi++)
#pragma unroll
    for (int ni=0;ni<4;ni++)
#pragma unroll
      for (int r=0;r<4;r++) o[mi][ni][r] = 0.f;

#pragma unroll
  for (int kk=0; kk<8; ++kk) {
    bf16x8 pa[2];
#pragma unroll
    for (int mi=0; mi<2; ++mi) {
      const int row = (wid<<5) + (mi<<4) + r15;
      const int ch = (kk<<2) + q;
      const int chs = (ch & 24) | ((ch ^ (row & 7)) & 7);
      pa[mi] = *(const bf16x8*)(Ps + (row<<8) + (chs<<3));
    }
#pragma unroll
    for (int ni=0; ni<4; ++ni) {
      const int vrow = (ni<<4) + r15;
      const int ch = (kk<<2) + q;
      const int chs = (ch & 24) | ((ch ^ (vrow & 7)) & 7);
      const bf16x8 bv = *(const bf16x8*)(Vs + (vrow<<8) + (chs<<3));
      o[0][ni] = __builtin_amdgcn_mfma_f32_16x16x32_bf16(pa[0], bv, o[0][ni], 0,0,0);
      o[1][ni] = __builtin_amdgcn_mfma_f32_16x16x32_bf16(pa[1], bv, o[1][ni], 0,0,0);
    }
  }
#pragma unroll
  for (int mi=0; mi<2; ++mi)
#pragma unroll
    for (int ni=0; ni<4; ++ni)
#pragma unroll
      for (int r=0; r<4; ++r) {
        const long long m = mBase + (wid<<5) + (mi<<4) + (q<<2) + r;
        ao[m*512 + (h<<6) + (ni<<4) + r15] = f2bf(o[mi][ni][r]);
      }
}

// ---------------- double layernorm (wave-per-row) + column-sum partials + scp zero --------
__global__ __launch_bounds__(256) void ln64_k(
    const unsigned short* __restrict__ attno, const unsigned short* __restrict__ feat,
    const float* __restrict__ g1, const float* __restrict__ b1,
    const float* __restrict__ g2, const float* __restrict__ b2,
    unsigned short* __restrict__ att, float* __restrict__ colp, float* __restrict__ scp)
{
  __shared__ float cred[4][512];
  const int tid = threadIdx.x, lane = tid & 63, wid = tid >> 6;
  const int c0 = lane << 3;
  scp[((long long)blockIdx.x<<8) + tid] = 0.f;
  float g1v[8], b1v[8], g2v[8], b2v[8];
#pragma unroll
  for (int j=0;j<8;j++){ g1v[j]=g1[c0+j]; b1v[j]=b1[c0+j]; g2v[j]=g2[c0+j]; b2v[j]=b2[c0+j]; }
  float cacc[8];
#pragma unroll
  for (int j=0;j<8;j++) cacc[j]=0.f;
  for (int rr=0; rr<16; ++rr) {
    const long long row = ((long long)blockIdx.x<<6) + (rr<<2) + wid;
    const bf16x8 a = *(const bf16x8*)(attno + (row<<9) + c0);
    const bf16x8 f = *(const bf16x8*)(feat  + (row<<9) + c0);
    float xv[8]; float s=0.f, qs=0.f;
#pragma unroll
    for (int j=0;j<8;j++){ xv[j] = bf2f((unsigned short)a[j]) + bf2f((unsigned short)f[j]); s += xv[j]; qs += xv[j]*xv[j]; }
#pragma unroll
    for (int o=32;o;o>>=1){ s += __shfl_xor(s,o,64); qs += __shfl_xor(qs,o,64); }
    float m = s*(1.f/512.f);
    float rs = rsqrtf(qs*(1.f/512.f) - m*m + 1e-5f);
    float y[8]; s=0.f; qs=0.f;
#pragma unroll
    for (int j=0;j<8;j++){ y[j] = (xv[j]-m)*rs*g1v[j] + b1v[j]; s += y[j]; qs += y[j]*y[j]; }
#pragma unroll
    for (int o=32;o;o>>=1){ s += __shfl_xor(s,o,64); qs += __shfl_xor(qs,o,64); }
    m = s*(1.f/512.f);
    rs = rsqrtf(qs*(1.f/512.f) - m*m + 1e-5f);
    bf16x8 ov;
#pragma unroll
    for (int j=0;j<8;j++){ const float z = (y[j]-m)*rs*g2v[j] + b2v[j]; cacc[j] += z; ov[j] = (short)f2bf(z); }
    *(bf16x8*)(att + (row<<9) + c0) = ov;
  }
#pragma unroll
  for (int j=0;j<8;j++) cred[wid][c0+j] = cacc[j];
  __syncthreads();
  {
    const float v0 = cred[0][tid]+cred[1][tid]+cred[2][tid]+cred[3][tid];
    const float v1 = cred[0][tid+256]+cred[1][tid+256]+cred[2][tid+256]+cred[3][tid+256];
    colp[((long long)blockIdx.x<<9)+tid]     = v0;
    colp[((long long)blockIdx.x<<9)+tid+256] = v1;
  }
}

// ---------------- gates / moe stats / bag / classifier ----------------
__global__ __launch_bounds__(512) void meangates_k(const float* __restrict__ part,
    const float* __restrict__ gw, const float* __restrict__ gb, float* __restrict__ gates)
{
  __shared__ float mv[512];
  __shared__ float tmp[4];
  const int t = threadIdx.x;
  float s = 0.f;
  for (int b=0;b<256;b++) s += part[(b<<9)+t];
  mv[t] = s * (1.f/16384.f);
  __syncthreads();
  if (t < 4) {
    float a = gb[t];
    for (int d=0; d<512; ++d) a += mv[d]*gw[d*4+t];
    tmp[t] = a;
  }
  __syncthreads();
  if (t == 0) {
    const float m = fmaxf(fmaxf(tmp[0],tmp[1]),fmaxf(tmp[2],tmp[3]));
    float e[4]; float ss=0.f;
    for (int i=0;i<4;i++){ e[i]=__expf(tmp[i]-m); ss+=e[i]; }
    for (int i=0;i<4;i++) gates[i] = e[i]/ss;
  }
}

__global__ __launch_bounds__(1024) void moestat_k(const float* __restrict__ sc,
                                                  float* __restrict__ mstat, float* __restrict__ sstat)
{
  __shared__ float red[1024];
  const int e = blockIdx.x, t = threadIdx.x;
  const float* p = sc + e*16384;
  float m = -3.4e38f;
  for (int n=t; n<16384; n+=1024) m = fmaxf(m, p[n]);
  red[t] = m; __syncthreads();
  for (int o=512;o;o>>=1){ if (t<o) red[t]=fmaxf(red[t],red[t+o]); __syncthreads(); }
  m = red[0]; __syncthreads();
  float s = 0.f;
  for (int n=t; n<16384; n+=1024) s += __expf(p[n]-m);
  red[t] = s; __syncthreads();
  for (int o=512;o;o>>=1){ if (t<o) red[t]+=red[t+o]; __syncthreads(); }
  if (t==0){ mstat[e]=m; sstat[e]=red[0]; }
}

__global__ __launch_bounds__(256) void wbag_k(const unsigned short* __restrict__ att,
    const float* __restrict__ scp, const float* __restrict__ gates,
    const float* __restrict__ mstat, const float* __restrict__ sstat,
    float* __restrict__ part, float* __restrict__ dout)
{
  __shared__ float wrow[128];
  const int c = threadIdx.x;
  const long long r0 = (long long)blockIdx.x * 128;
  if (c < 128) {
    const long long n = r0 + c;
    float w = 0.f;
#pragma unroll
    for (int e=0;e<4;e++) w += gates[e]*__expf(scp[((long long)e<<14)+n]-mstat[e]) / sstat[e];
    wrow[c] = w;
    dout[514 + n] = w;
  }
  __syncthreads();
  float a0=0.f, a1=0.f;
  for (int r=0;r<128;r++){
    const float w = wrow[r];
    const unsigned short* p = att + ((r0+r)<<9);
    a0 += w*bf2f(p[c]); a1 += w*bf2f(p[c+256]);
  }
  part[((long long)blockIdx.x<<9)+c]     = a0;
  part[((long long)blockIdx.x<<9)+c+256] = a1;
}

__global__ __launch_bounds__(512) void cls2_k(const float* __restrict__ bagp,
    const float* __restrict__ w1, const float* __restrict__ b1,
    const float* __restrict__ w2, const float* __restrict__ b2,
    const float* __restrict__ w3, const float* __restrict__ b3, float* __restrict__ dout)
{
  __shared__ float bag[512]; __shared__ float c1[256]; __shared__ float c2[128];
  const int tid = threadIdx.x;
  float s = 0.f;
  for (int b=0;b<128;b++) s += bagp[(b<<9)+tid];
  bag[tid] = s; dout[tid] = s;
  __syncthreads();
  if (tid < 256) {
    float a = b1[tid];
    for (int d=0; d<512; ++d) a += bag[d]*w1[d*256+tid];
    c1[tid] = fmaxf(a, 0.f);
  }
  __syncthreads();
  if (tid < 128) {
    float a2 = b2[tid];
    for (int d=0; d<256; ++d) a2 += c1[d]*w2[d*128+tid];
    c2[tid] = fmaxf(a2, 0.f);
  }
  __syncthreads();
  if (tid < 2) {
    float a3 = b3[tid];
    for (int d=0; d<128; ++d) a3 += c2[d]*w3[d*2+tid];
    dout[512 + tid] = a3;
  }
}

extern "C" void kernel_launch(void* const* d_in, const int* in_sizes, int n_in,
                              void* d_out, int out_size, void* d_ws, size_t ws_size,
                              hipStream_t stream)
{
  (void)in_sizes; (void)n_in; (void)out_size; (void)ws_size;
  const float* x      = (const float*)d_in[0];
  const float* enc_w1 = (const float*)d_in[1];
  const float* enc_b1 = (const float*)d_in[2];
  const float* enc_w2 = (const float*)d_in[3];
  const float* enc_b2 = (const float*)d_in[4];
  const float* enc_w3 = (const float*)d_in[5];
  const float* enc_b3 = (const float*)d_in[6];
  const float* q_w    = (const float*)d_in[7];
  const float* q_b    = (const float*)d_in[8];
  const float* k_w    = (const float*)d_in[9];
  const float* k_b    = (const float*)d_in[10];
  const float* v_w    = (const float*)d_in[11];
  const float* v_b    = (const float*)d_in[12];
  const float* o_w    = (const float*)d_in[13];
  const float* o_b    = (const float*)d_in[14];
  const float* E_w    = (const float*)d_in[15];
  const float* F_w    = (const float*)d_in[16];
  const float* ln1_g  = (const float*)d_in[17];
  const float* ln1_b  = (const float*)d_in[18];
  const float* ln2_g  = (const float*)d_in[19];
  const float* ln2_b  = (const float*)d_in[20];
  const float* gate_w = (const float*)d_in[21];
  const float* gate_b = (const float*)d_in[22];
  const float* moe_w1 = (const float*)d_in[23];
  const float* moe_b1 = (const float*)d_in[24];
  const float* moe_w2 = (const float*)d_in[25];
  // d_in[26] = moe_b2: drops out of the row-softmax (shift invariance)
  const float* cls_w1 = (const float*)d_in[27];
  const float* cls_b1 = (const float*)d_in[28];
  const float* cls_w2 = (const float*)d_in[29];
  const float* cls_b2 = (const float*)d_in[30];
  const float* cls_w3 = (const float*)d_in[31];
  const float* cls_b3 = (const float*)d_in[32];

  char* ws = (char*)d_ws;
  const size_t MB = 1024*1024;
  unsigned short* x_bf  = (unsigned short*)(ws + 0);          // [16384][2048]  64MB
  unsigned short* h1    = (unsigned short*)(ws + 64*MB);      // [16384][1024]  32MB
  unsigned short* h2    = (unsigned short*)(ws + 0);          // 16MB (x_bf dead)
  unsigned short* feat  = (unsigned short*)(ws + 16*MB);      // 16MB
  unsigned short* qkv   = (unsigned short*)(ws + 32*MB);      // [16384][1536]  48MB (h1 dead)
  unsigned short* ao    = (unsigned short*)(ws + 80*MB);      // 16MB
  unsigned short* attno = (unsigned short*)(ws + 0);          // 16MB (h2 dead)
  unsigned short* att   = (unsigned short*)(ws + 96*MB);      // 16MB
  unsigned short* w1t   = (unsigned short*)(ws + 112*MB);                 // [1024][2048] 4MB
  unsigned short* w2t   = (unsigned short*)(ws + 116*MB);                 // 1MB
  unsigned short* w3t   = (unsigned short*)(ws + 117*MB);                 // 0.5MB
  unsigned short* qkvw  = (unsigned short*)(ws + 117*MB + 512*1024);      // 1.5MB
  unsigned short* owt   = (unsigned short*)(ws + 119*MB);                 // 0.5MB
  unsigned short* mwt   = (unsigned short*)(ws + 119*MB + 512*1024);      // 1MB
  float*  t1b   = (float*)(ws + 120*MB + 512*1024);                       // 0.5MB
  float*  redb  = (float*)(ws + 121*MB);                                  // 1MB
  unsigned short* Kcbf  = (unsigned short*)(ws + 122*MB);                 // 256KB
  unsigned short* Vctbf = (unsigned short*)(ws + 122*MB + 256*1024);      // 256KB
  float*  colp  = (float*)(ws + 122*MB + 512*1024);                       // [256][512] 512KB
  float*  bagp  = (float*)(ws + 123*MB);                                  // [128][512] 256KB
  float*  qkvb  = (float*)(ws + 123*MB + 256*1024);                       // 6KB
  float*  gatesp= (float*)(ws + 123*MB + 264*1024);
  float*  scp   = (float*)(ws + 123*MB + 268*1024);                       // [4][16384] 256KB
  float*  mstat = (float*)(ws + 123*MB + 524*1024);
  float*  sstat = (float*)(ws + 123*MB + 524*1024 + 64);
  float*  dout  = (float*)d_out;

  // ---- mega prep (t1, transposes, pad-zero, lane-contiguous x convert) ----
  prep_k<<<4033,256,0,stream>>>(x, x_bf, enc_w1, w1t, enc_w2, w2t,
                                enc_w3, q_w, k_w, v_w, o_w, w3t, qkvw, owt,
                                moe_w1, mwt, E_w, F_w, t1b, q_b, k_b, v_b, qkvb);

  // ---- encoder ----
  gemm4_k<1,false><<<dim3(4,64,1),512,0,stream>>>(x_bf, w1t, enc_b1, h1, nullptr,nullptr, 2048,2048,2048,1024);
  gemm5_k<1><<<dim3(4,128,1),256,0,stream>>>(h1, w2t, enc_b2, h2,   1024,1024,1024, 512);
  gemm5_k<1><<<dim3(4,128,1),256,0,stream>>>(h2, w3t, enc_b3, feat,  512, 512, 512, 512);
  // ---- QKV (merged, N=1536) ----
  gemm5_k<0><<<dim3(12,128,1),256,0,stream>>>(feat, qkvw, qkvb, qkv, 512,512,512,1536);
  // ---- linformer projections ----
  red_k<<<dim3(256,2),512,0,stream>>>(qkv, redb);
  kc_k <<<dim3(256,2),512,0,stream>>>(t1b, redb, Kcbf, Vctbf);
  // ---- fused attention ----
  attn_k<<<dim3(128,8),256,0,stream>>>(qkv, Kcbf, Vctbf, ao);
  // ---- output projection + residual + double LN (+ colsum partials + scp zero) ----
  gemm5_k<0><<<dim3(4,128,1),256,0,stream>>>(ao, owt, o_b, attno, 512,512,512,512);
  ln64_k<<<256,256,0,stream>>>(attno, feat, ln1_g, ln1_b, ln2_g, ln2_b, att, colp, scp);
  meangates_k<<<1,512,0,stream>>>(colp, gate_w, gate_b, gatesp);
  // ---- MoE expert attention: ONE merged N=1024 GEMM, tanh+dot fused in epilogue ----
  gemm4_k<0,true><<<dim3(4,64,1),512,0,stream>>>(att, mwt, moe_b1, nullptr, moe_w2, scp, 512,512,512,0);
  moestat_k<<<4,1024,0,stream>>>(scp, mstat, sstat);
  // ---- attn weights + bag partials (fused) + classifier ----
  wbag_k<<<128,256,0,stream>>>(att, scp, gatesp, mstat, sstat, bagp, dout);
  cls2_k<<<1,512,0,stream>>>(bagp, cls_w1, cls_b1, cls_w2, cls_b2, cls_w3, cls_b3, dout);
}

// Round 13
// 428.642 us; speedup vs baseline: 1.1274x; 1.0091x over previous
//
#include <hip/hip_runtime.h>

#define DI __device__ __forceinline__

DI float bf2f(unsigned short u){ unsigned int v = ((unsigned int)u)<<16; float f; __builtin_memcpy(&f,&v,4); return f; }
DI unsigned short f2bf(float f){ unsigned int v; __builtin_memcpy(&v,&f,4); v = v + 0x7FFFu + ((v>>16)&1u); return (unsigned short)(v>>16); }

typedef __attribute__((ext_vector_type(8))) short bf16x8;
typedef __attribute__((ext_vector_type(4))) short short4v;
typedef __attribute__((ext_vector_type(4))) float f32x4;

#define GLD_LDS16(src, dst) __builtin_amdgcn_global_load_lds( \
    (const __attribute__((address_space(1))) void*)(src), \
    (__attribute__((address_space(3))) void*)(dst), 16, 0, 0)

DI void barrier_() { asm volatile("" ::: "memory"); __builtin_amdgcn_s_barrier(); asm volatile("" ::: "memory"); }

// ---------------- gemm5: 128x128 tile, 4-phase counted-vmcnt pipeline (2 barriers/tile) ----
template<int ACT>
__global__ __launch_bounds__(256,2) void gemm5_k(
    const unsigned short* __restrict__ A, const unsigned short* __restrict__ Bt,
    const float* __restrict__ bias, unsigned short* __restrict__ C,
    int K, int lda, int ldb, int ldc)
{
  __shared__ unsigned short As[2][8192];
  __shared__ unsigned short Bs[2][8192];
  const int tid = threadIdx.x, lane = tid & 63, wid = tid >> 6;
  const int wm = wid >> 1, wn = wid & 1;
  const int q = lane >> 4, r15 = lane & 15;
  const int nx = gridDim.x;
  const int bid = blockIdx.x + nx*blockIdx.y;
  const int cpx = (nx*gridDim.y) >> 3;
  const int wg = (bid & 7)*cpx + (bid >> 3);
  const long long mBase = (long long)(wg / nx) << 7;
  const long long nBase = (long long)(wg % nx) << 7;

  f32x4 acc[4][4];
#pragma unroll
  for (int i=0;i<4;i++)
#pragma unroll
    for (int j=0;j<4;j++)
#pragma unroll
      for (int r=0;r<4;r++) acc[i][j][r] = 0.f;

  const int NT = K >> 6;

#define G5_STA(j, nb, kk) { const int d_ = tid + ((j)<<8); const int row_ = d_>>3, c_ = d_&7, sc_ = c_ ^ (row_&7); \
    GLD_LDS16(A + (mBase+row_)*(long long)lda + (kk) + (sc_<<3), &As[nb][d_<<3]); }
#define G5_STB(j, nb, kk) { const int d_ = tid + ((j)<<8); const int row_ = d_>>3, c_ = d_&7, sc_ = c_ ^ (row_&7); \
    GLD_LDS16(Bt + (nBase+row_)*(long long)ldb + (kk) + (sc_<<3), &Bs[nb][d_<<3]); }

  G5_STB(0,0,0); G5_STB(2,0,0); G5_STB(1,0,0); G5_STB(3,0,0);
  G5_STA(0,0,0); G5_STA(2,0,0); G5_STA(1,0,0); G5_STA(3,0,0);

  for (int t=0; t<NT; ++t) {
    const int b = t & 1, nb = b ^ 1;
    const bool more = (t+1 < NT);
    const int k1 = (t+1) << 6;
    bf16x8 aL[4], aH[4], bL[4], bH[4];

    // ---- phase 0: (m-lo, n-lo). (vmcnt, barrier) pair: tile-t data visible; buf nb free.
    asm volatile("s_waitcnt vmcnt(2)" ::: "memory");
    barrier_();
#pragma unroll
    for (int mi=0; mi<2; ++mi)
#pragma unroll
      for (int ks=0; ks<2; ++ks) {
        const int row = (wm<<6) + (mi<<4) + r15;
        const int ch = ((ks<<2)+q) ^ (row&7);
        aL[mi*2+ks] = *(const bf16x8*)&As[b][(row<<6) + (ch<<3)];
      }
#pragma unroll
    for (int ni=0; ni<2; ++ni)
#pragma unroll
      for (int ks=0; ks<2; ++ks) {
        const int col = (wn<<6) + (ni<<4) + r15;
        const int ch = ((ks<<2)+q) ^ (col&7);
        bL[ni*2+ks] = *(const bf16x8*)&Bs[b][(col<<6) + (ch<<3)];
      }
    if (more) { G5_STB(0,nb,k1); G5_STB(2,nb,k1); }
    __builtin_amdgcn_s_setprio(1);
#pragma unroll
    for (int mi=0; mi<2; ++mi)
#pragma unroll
      for (int ni=0; ni<2; ++ni)
#pragma unroll
        for (int ks=0; ks<2; ++ks)
          acc[mi][ni] = __builtin_amdgcn_mfma_f32_16x16x32_bf16(aL[mi*2+ks], bL[ni*2+ks], acc[mi][ni], 0,0,0);
    __builtin_amdgcn_s_setprio(0);
    // (ph0-end barrier removed: ph1 reads buf b only; in-flight writes target nb)

    // ---- phase 1: (m-lo, n-hi)
#pragma unroll
    for (int ni=0; ni<2; ++ni)
#pragma unroll
      for (int ks=0; ks<2; ++ks) {
        const int col = (wn<<6) + ((ni+2)<<4) + r15;
        const int ch = ((ks<<2)+q) ^ (col&7);
        bH[ni*2+ks] = *(const bf16x8*)&Bs[b][(col<<6) + (ch<<3)];
      }
    if (more) { G5_STB(1,nb,k1); G5_STB(3,nb,k1); }
    __builtin_amdgcn_s_setprio(1);
#pragma unroll
    for (int mi=0; mi<2; ++mi)
#pragma unroll
      for (int ni=0; ni<2; ++ni)
#pragma unroll
        for (int ks=0; ks<2; ++ks)
          acc[mi][ni+2] = __builtin_amdgcn_mfma_f32_16x16x32_bf16(aL[mi*2+ks], bH[ni*2+ks], acc[mi][ni+2], 0,0,0);
    __builtin_amdgcn_s_setprio(0);

    // ---- phase 2: (m-hi, n-lo). (vmcnt, barrier) pair: all waves' A-hi slices landed.
    if (more) { asm volatile("s_waitcnt vmcnt(4)" ::: "memory"); }
    else      { asm volatile("s_waitcnt vmcnt(0)" ::: "memory"); }
    barrier_();
#pragma unroll
    for (int mi=0; mi<2; ++mi)
#pragma unroll
      for (int ks=0; ks<2; ++ks) {
        const int row = (wm<<6) + ((mi+2)<<4) + r15;
        const int ch = ((ks<<2)+q) ^ (row&7);
        aH[mi*2+ks] = *(const bf16x8*)&As[b][(row<<6) + (ch<<3)];
      }
    if (more) { G5_STA(0,nb,k1); G5_STA(2,nb,k1); }
    __builtin_amdgcn_s_setprio(1);
#pragma unroll
    for (int mi=0; mi<2; ++mi)
#pragma unroll
      for (int ni=0; ni<2; ++ni)
#pragma unroll
        for (int ks=0; ks<2; ++ks)
          acc[mi+2][ni] = __builtin_amdgcn_mfma_f32_16x16x32_bf16(aH[mi*2+ks], bL[ni*2+ks], acc[mi+2][ni], 0,0,0);
    __builtin_amdgcn_s_setprio(0);
    // (ph2-end barrier removed: ph3 reads registers only; stage targets nb)

    // ---- phase 3: (m-hi, n-hi)
    if (more) { G5_STA(1,nb,k1); G5_STA(3,nb,k1); }
    __builtin_amdgcn_s_setprio(1);
#pragma unroll
    for (int mi=0; mi<2; ++mi)
#pragma unroll
      for (int ni=0; ni<2; ++ni)
#pragma unroll
        for (int ks=0; ks<2; ++ks)
          acc[mi+2][ni+2] = __builtin_amdgcn_mfma_f32_16x16x32_bf16(aH[mi*2+ks], bH[ni*2+ks], acc[mi+2][ni+2], 0,0,0);
    __builtin_amdgcn_s_setprio(0);
  }
#undef G5_STA
#undef G5_STB

#pragma unroll
  for (int ni=0; ni<4; ++ni) {
    const long long n = nBase + (wn<<6) + (ni<<4) + r15;
    const float bval = bias[n];
#pragma unroll
    for (int mi=0; mi<4; ++mi) {
#pragma unroll
      for (int r=0; r<4; ++r) {
        const long long m = mBase + (wm<<6) + (mi<<4) + (q<<2) + r;
        float v = acc[mi][ni][r] + bval;
        if constexpr (ACT==1) v = fmaxf(v, 0.f);
        C[m*(long long)ldc + n] = f2bf(v);
      }
    }
  }
}

// ---------------- gemm4: 256x256 tile, 4-phase counted-vmcnt pipeline (2 barriers/tile) ----
template<int ACT, bool MOE>
__global__ __launch_bounds__(512,2) void gemm4_k(
    const unsigned short* __restrict__ A, const unsigned short* __restrict__ Bt,
    const float* __restrict__ bias, unsigned short* __restrict__ C,
    const float* __restrict__ w2, float* __restrict__ scp,
    int K, int lda, int ldb, int ldc)
{
  __shared__ unsigned short As[2][16384];
  __shared__ unsigned short Bs[2][16384];
  const int tid = threadIdx.x, lane = tid & 63, wid = tid >> 6;
  const int wm = wid >> 2, wn = wid & 3;
  const int q = lane >> 4, r15 = lane & 15;
  const int nx = gridDim.x;
  const int bid = blockIdx.x + nx*blockIdx.y;
  const int cpx = (nx*gridDim.y) >> 3;
  const int wg = (bid & 7)*cpx + (bid >> 3);
  const long long mBase = (long long)(wg / nx) << 8;
  const long long nBase = (long long)(wg % nx) << 8;

  f32x4 acc[8][4];
#pragma unroll
  for (int i=0;i<8;i++)
#pragma unroll
    for (int j=0;j<4;j++)
#pragma unroll
      for (int r=0;r<4;r++) acc[i][j][r] = 0.f;

  const int NT = K >> 6;

#define G4_STA(j, nb, kk) { const int d_ = tid + ((j)<<9); const int row_ = d_>>3, c_ = d_&7, sc_ = c_ ^ (row_&7); \
    GLD_LDS16(A + (mBase+row_)*(long long)lda + (kk) + (sc_<<3), &As[nb][d_<<3]); }
#define G4_STB(j, nb, kk) { const int d_ = tid + ((j)<<9); const int row_ = d_>>3, c_ = d_&7, sc_ = c_ ^ (row_&7); \
    GLD_LDS16(Bt + (nBase+row_)*(long long)ldb + (kk) + (sc_<<3), &Bs[nb][d_<<3]); }

  G4_STB(0,0,0); G4_STB(1,0,0); G4_STB(2,0,0); G4_STB(3,0,0);
  G4_STA(0,0,0); G4_STA(2,0,0); G4_STA(1,0,0); G4_STA(3,0,0);

  for (int t=0; t<NT; ++t) {
    const int b = t & 1, nb = b ^ 1;
    const bool more = (t+1 < NT);
    const int k1 = (t+1) << 6;
    bf16x8 aF[8], bL[4], bH[4];

    // ---- phase 0
    asm volatile("s_waitcnt vmcnt(2)" ::: "memory");
    barrier_();
#pragma unroll
    for (int mi=0; mi<4; ++mi)
#pragma unroll
      for (int ks=0; ks<2; ++ks) {
        const int row = (wm<<7) + (mi<<4) + r15;
        const int ch = ((ks<<2)+q) ^ (row&7);
        aF[mi*2+ks] = *(const bf16x8*)&As[b][(row<<6) + (ch<<3)];
      }
#pragma unroll
    for (int ni=0; ni<2; ++ni)
#pragma unroll
      for (int ks=0; ks<2; ++ks) {
        const int col = (wn<<6) + (ni<<4) + r15;
        const int ch = ((ks<<2)+q) ^ (col&7);
        bL[ni*2+ks] = *(const bf16x8*)&Bs[b][(col<<6) + (ch<<3)];
      }
    if (more) { G4_STB(0,nb,k1); G4_STB(1,nb,k1); }
    __builtin_amdgcn_s_setprio(1);
#pragma unroll
    for (int mi=0; mi<4; ++mi)
#pragma unroll
      for (int ni=0; ni<2; ++ni)
#pragma unroll
        for (int ks=0; ks<2; ++ks)
          acc[mi][ni] = __builtin_amdgcn_mfma_f32_16x16x32_bf16(aF[mi*2+ks], bL[ni*2+ks], acc[mi][ni], 0,0,0);
    __builtin_amdgcn_s_setprio(0);
    // (ph0-end barrier removed)

    // ---- phase 1
#pragma unroll
    for (int ni=0; ni<2; ++ni)
#pragma unroll
      for (int ks=0; ks<2; ++ks) {
        const int col = (wn<<6) + ((ni+2)<<4) + r15;
        const int ch = ((ks<<2)+q) ^ (col&7);
        bH[ni*2+ks] = *(const bf16x8*)&Bs[b][(col<<6) + (ch<<3)];
      }
    if (more) { G4_STB(2,nb,k1); G4_STB(3,nb,k1); }
    __builtin_amdgcn_s_setprio(1);
#pragma unroll
    for (int mi=0; mi<4; ++mi)
#pragma unroll
      for (int ni=0; ni<2; ++ni)
#pragma unroll
        for (int ks=0; ks<2; ++ks)
          acc[mi][ni+2] = __builtin_amdgcn_mfma_f32_16x16x32_bf16(aF[mi*2+ks], bH[ni*2+ks], acc[mi][ni+2], 0,0,0);
    __builtin_amdgcn_s_setprio(0);

    // ---- phase 2
    if (more) { asm volatile("s_waitcnt vmcnt(4)" ::: "memory"); }
    else      { asm volatile("s_waitcnt vmcnt(0)" ::: "memory"); }
    barrier_();
#pragma unroll
    for (int mi=0; mi<4; ++mi)
#pragma unroll
      for (int ks=0; ks<2; ++ks) {
        const int row = (wm<<7) + ((mi+4)<<4) + r15;
        const int ch = ((ks<<2)+q) ^ (row&7);
        aF[mi*2+ks] = *(const bf16x8*)&As[b][(row<<6) + (ch<<3)];
      }
    if (more) { G4_STA(0,nb,k1); G4_STA(2,nb,k1); }
    __builtin_amdgcn_s_setprio(1);
#pragma unroll
    for (int mi=0; mi<4; ++mi)
#pragma unroll
      for (int ni=0; ni<2; ++ni)
#pragma unroll
        for (int ks=0; ks<2; ++ks)
          acc[mi+4][ni] = __builtin_amdgcn_mfma_f32_16x16x32_bf16(aF[mi*2+ks], bL[ni*2+ks], acc[mi+4][ni], 0,0,0);
    __builtin_amdgcn_s_setprio(0);
    // (ph2-end barrier removed)

    // ---- phase 3
    if (more) { G4_STA(1,nb,k1); G4_STA(3,nb,k1); }
    __builtin_amdgcn_s_setprio(1);
#pragma unroll
    for (int mi=0; mi<4; ++mi)
#pragma unroll
      for (int ni=0; ni<2; ++ni)
#pragma unroll
        for (int ks=0; ks<2; ++ks)
          acc[mi+4][ni+2] = __builtin_amdgcn_mfma_f32_16x16x32_bf16(aF[mi*2+ks], bH[ni*2+ks], acc[mi+4][ni+2], 0,0,0);
    __builtin_amdgcn_s_setprio(0);
  }
#undef G4_STA
#undef G4_STB

  if constexpr (MOE) {
    const int e = (int)(nBase >> 8);
#pragma unroll
    for (int mi=0; mi<8; ++mi) {
#pragma unroll
      for (int r=0; r<4; ++r) {
        float p = 0.f;
#pragma unroll
        for (int ni=0; ni<4; ++ni) {
          const int n = (int)nBase + (wn<<6) + (ni<<4) + r15;
          const float v = acc[mi][ni][r] + bias[n];
          const float th = 1.f - 2.f/(__expf(2.f*v) + 1.f);
          p += th * w2[n];
        }
        p += __shfl_xor(p,1,64); p += __shfl_xor(p,2,64);
        p += __shfl_xor(p,4,64); p += __shfl_xor(p,8,64);
        if (r15 == 0) {
          const long long m = mBase + (wm<<7) + (mi<<4) + (q<<2) + r;
          atomicAdd(scp + ((long long)e<<14) + m, p);
        }
      }
    }
  } else {
#pragma unroll
    for (int ni=0; ni<4; ++ni) {
      const long long n = nBase + (wn<<6) + (ni<<4) + r15;
      const float bval = bias[n];
#pragma unroll
      for (int mi=0; mi<8; ++mi) {
#pragma unroll
        for (int r=0; r<4; ++r) {
          const long long m = mBase + (wm<<7) + (mi<<4) + (q<<2) + r;
          float v = acc[mi][ni][r] + bval;
          if constexpr (ACT==1) v = fmaxf(v, 0.f);
          C[m*(long long)ldc + n] = f2bf(v);
        }
      }
    }
  }
}

// ---------------- mega prep ----------------
DI void transpose64(const float* __restrict__ src, unsigned short* __restrict__ dst,
                    int K, int N, int Kpad, int k0, int n0, float (*tile)[65], int tid)
{
  const int c = tid & 63, rg = tid >> 6;
#pragma unroll
  for (int j=0;j<16;j++){
    const int r = (j<<2) + rg;
    const int k = k0 + r;
    tile[r][c] = (k < K) ? src[(long long)k*N + n0 + c] : 0.f;
  }
  __syncthreads();
#pragma unroll
  for (int j=0;j<16;j++){
    const int nn = (j<<2) + rg;
    dst[(long long)(n0+nn)*Kpad + k0 + c] = f2bf(tile[c][nn]);
  }
}

__global__ __launch_bounds__(256) void prep_k(
    const float* __restrict__ x, unsigned short* __restrict__ xb,
    const float* __restrict__ enc_w1, unsigned short* __restrict__ w1t,
    const float* __restrict__ enc_w2, unsigned short* __restrict__ w2t,
    const float* __restrict__ enc_w3, const float* __restrict__ q_w,
    const float* __restrict__ k_w, const float* __restrict__ v_w, const float* __restrict__ o_w,
    unsigned short* __restrict__ w3t, unsigned short* __restrict__ qkvw, unsigned short* __restrict__ owt,
    const float* __restrict__ moe_w1, unsigned short* __restrict__ mwt,
    const float* __restrict__ Ew, const float* __restrict__ Fw, float* __restrict__ t1,
    const float* __restrict__ qb, const float* __restrict__ kb, const float* __restrict__ vb,
    float* __restrict__ qkvb)
{
  __shared__ float tile[64][65];
  const int b = blockIdx.x, tid = threadIdx.x;
  if (b < 512) {
    const int k = b & 255, which = b >> 8, c = tid;
    const float* Wr = (which ? Fw : Ew) + (long long)c*10000;
    const float ksc = 39.0625f, inv = 1.f/39.0625f;
    const float sf = (k + 0.5f)*ksc - 0.5f;
    int ilo = (int)ceilf(sf - ksc); if (ilo < 0) ilo = 0;
    int ihi = (int)floorf(sf + ksc); if (ihi > 9999) ihi = 9999;
    float acc = 0.f, wsum = 0.f;
    int i = ilo;
    for (; i + 8 <= ihi + 1; i += 8) {
      float v[8];
#pragma unroll
      for (int j=0;j<8;j++) v[j] = Wr[i+j];
#pragma unroll
      for (int j=0;j<8;j++){
        const float w = fmaxf(1.f - fabsf(sf - (float)(i+j))*inv, 0.f);
        acc += w*v[j]; wsum += w;
      }
    }
    for (; i <= ihi; ++i) {
      const float w = fmaxf(1.f - fabsf(sf - (float)i)*inv, 0.f);
      acc += w * Wr[i]; wsum += w;
    }
    t1[(which*256 + k)*256 + c] = acc / wsum;
  } else if (b < 1024) {
    const int bb = b - 512;
    transpose64(enc_w1, w1t, 2000, 1024, 2048, (bb&31)<<6, (bb>>5)<<6, tile, tid);
  } else if (b < 1152) {
    const int bb = b - 1024;
    transpose64(enc_w2, w2t, 1024, 512, 1024, (bb&15)<<6, (bb>>4)<<6, tile, tid);
  } else if (b < 1472) {
    const int bb = b - 1152;
    const int z = bb >> 6, r = bb & 63;
    const float* s = (z==0)?enc_w3:(z==1)?q_w:(z==2)?k_w:(z==3)?v_w:o_w;
    unsigned short* d = (z==0)?w3t:(z==1)?qkvw:(z==2)?(qkvw+512*512):(z==3)?(qkvw+1024*512):owt;
    transpose64(s, d, 512, 512, 512, (r&7)<<6, (r>>3)<<6, tile, tid);
  } else if (b < 1600) {
    const int bb = b - 1472;
    const int z = bb >> 5, r = bb & 31;
    transpose64(moe_w1 + (long long)z*512*256, mwt + (long long)z*256*512,
                512, 256, 512, (r&7)<<6, (r>>3)<<6, tile, tid);
  } else if (b == 1600) {
#pragma unroll
    for (int i=0;i<6;i++){
      const int idx = i*256 + tid;
      const int wq = idx >> 9, off = idx & 511;
      const float* src = (wq==0)?qb:(wq==1)?kb:vb;
      qkvb[idx] = src[off];
    }
  } else if (b < 1985) {
    const int p = (b - 1601)*256 + tid;
    const int row = p / 6, cc = p - row*6;
    bf16x8 z8;
#pragma unroll
    for (int j=0;j<8;j++) z8[j]=0;
    *(bf16x8*)(xb + (long long)row*2048 + 2000 + cc*8) = z8;
  } else {
    const int bb = b - 1985;
    const long long base = (long long)bb*256 + tid;
#pragma unroll
    for (int j=0;j<16;j++){
      const long long id = base + (long long)j*524288;
      if (id < 8192000) {
        const float4 f = *((const float4*)x + id);
        const long long row = id / 500;
        const int col = (int)(id - row*500);
        short4v o;
        o[0]=(short)f2bf(f.x); o[1]=(short)f2bf(f.y); o[2]=(short)f2bf(f.z); o[3]=(short)f2bf(f.w);
        *(short4v*)(xb + row*2048 + (long long)col*4) = o;
      }
    }
  }
}

// ---------------- linformer projection helpers ----------------
__global__ __launch_bounds__(512) void red_k(const unsigned short* __restrict__ qkv,
                                             float* __restrict__ red)
{
  const int c = blockIdx.x, which = blockIdx.y, j = threadIdx.x;
  const unsigned short* X = qkv + (which ? 1024 : 512);
  int nlo = 64*c - 32; if (nlo < 0) nlo = 0;
  int nhi = 64*c + 95; if (nhi > 16383) nhi = 16383;
  float acc = 0.f;
  for (int n=nlo; n<=nhi; ++n) {
    float sf = (n + 0.5f)*0.015625f - 0.5f;
    sf = fminf(fmaxf(sf, 0.f), 255.f);
    const int c0 = (int)sf;
    const float f = sf - (float)c0;
    float w = 0.f;
    if (c == c0) w = 1.f - f;
    else if (c == c0+1) w = f;
    if (w != 0.f) acc += w * bf2f(X[(long long)n*1536 + j]);
  }
  red[(which*256 + c)*512 + j] = acc;
}

__global__ __launch_bounds__(512) void kc_k(const float* __restrict__ t1, const float* __restrict__ red,
                                            unsigned short* __restrict__ Kc, unsigned short* __restrict__ Vct)
{
  const int k = blockIdx.x, which = blockIdx.y, j = threadIdx.x;
  const float* T = t1 + (which*256 + k)*256;
  const float* R = red + which*131072;
  float acc = 0.f;
  for (int c=0; c<256; ++c) acc += T[c] * R[c*512 + j];
  const int h = j >> 6, d = j & 63;
  if (which == 0) Kc [(h<<14) + (k<<6) + d] = f2bf(acc);
  else            Vct[(h<<14) + (d<<8) + k] = f2bf(acc);
}

// ---------------- fused linformer attention ----------------
__global__ __launch_bounds__(256) void attn_k(
    const unsigned short* __restrict__ Qg, const unsigned short* __restrict__ Kc,
    const unsigned short* __restrict__ Vct, unsigned short* __restrict__ ao)
{
  __shared__ unsigned short Ks[16384];
  __shared__ unsigned short Vs[16384];
  __shared__ unsigned short Ps[32768];
  const int h = blockIdx.y;
  const long long mBase = (long long)blockIdx.x << 7;
  const int tid = threadIdx.x, lane = tid & 63, wid = tid >> 6;
  const int q = lane >> 4, r15 = lane & 15;

#pragma unroll
  for (int it=0; it<8; ++it) {
    const int dbase = (it<<8) + (wid<<6);
    const int d = dbase + lane;
    {
      const int row = d >> 3, cc = d & 7, sc = cc ^ (row & 7);
      GLD_LDS16(Kc + (h<<14) + (row<<6) + (sc<<3), Ks + (dbase<<3));
    }
    {
      const int row = d >> 5, cc = d & 31, sc = (cc & 24) | ((cc ^ (row & 7)) & 7);
      GLD_LDS16(Vct + (h<<14) + (row<<8) + (sc<<3), Vs + (dbase<<3));
    }
  }
  __syncthreads();

  f32x4 acc[2][16];
#pragma unroll
  for (int mi=0;mi<2;mi++)
#pragma unroll
    for (int ni=0;ni<16;ni++)
#pragma unroll
      for (int r=0;r<4;r++) acc[mi][ni][r] = 0.f;

#pragma unroll
  for (int ks=0; ks<2; ++ks) {
    bf16x8 af[2];
#pragma unroll
    for (int mi=0; mi<2; ++mi) {
      const long long m = mBase + (wid<<5) + (mi<<4) + r15;
      af[mi] = *(const bf16x8*)(Qg + m*1536 + (h<<6) + (ks<<5) + (q<<3));
    }
#pragma unroll
    for (int ni=0; ni<16; ++ni) {
      const int col = (ni<<4) + r15;
      const int ch = ((ks<<2)+q) ^ (col&7);
      const bf16x8 bv = *(const bf16x8*)(Ks + (col<<6) + (ch<<3));
      acc[0][ni] = __builtin_amdgcn_mfma_f32_16x16x32_bf16(af[0], bv, acc[0][ni], 0,0,0);
      acc[1][ni] = __builtin_amdgcn_mfma_f32_16x16x32_bf16(af[1], bv, acc[1][ni], 0,0,0);
    }
  }

#pragma unroll
  for (int mi=0; mi<2; ++mi) {
#pragma unroll
    for (int r=0; r<4; ++r) {
      float mx = -3.4e38f;
#pragma unroll
      for (int ni=0; ni<16; ++ni) mx = fmaxf(mx, acc[mi][ni][r]);
      mx = fmaxf(mx, __shfl_xor(mx,1,64)); mx = fmaxf(mx, __shfl_xor(mx,2,64));
      mx = fmaxf(mx, __shfl_xor(mx,4,64)); mx = fmaxf(mx, __shfl_xor(mx,8,64));
      float s = 0.f;
#pragma unroll
      for (int ni=0; ni<16; ++ni) {
        const float e = __expf((acc[mi][ni][r] - mx)*0.125f);
        acc[mi][ni][r] = e; s += e;
      }
      s += __shfl_xor(s,1,64); s += __shfl_xor(s,2,64);
      s += __shfl_xor(s,4,64); s += __shfl_xor(s,8,64);
      const float inv = 1.f / s;
      const int row = (wid<<5) + (mi<<4) + (q<<2) + r;
#pragma unroll
      for (int ni=0; ni<16; ++ni) {
        const int col = (ni<<4) + r15;
        const int ch = col >> 3;
        const int chs = (ch & 24) | ((ch ^ (row & 7)) & 7);
        Ps[(row<<8) + (chs<<3) + (col&7)] = f2bf(acc[mi][ni][r]*inv);
      }
    }
  }
  __syncthreads();

  f32x4 o[2][4];
#pragma unroll
  for (int mi=0;mi<2;mi++)
#pragma unroll
    for (int ni=0;ni<4;ni++)
#pragma unroll
      for (int r=0;r<4;r++) o[mi][ni][r] = 0.f;

#pragma unroll
  for (int kk=0; kk<8; ++kk) {
    bf16x8 pa[2];
#pragma unroll
    for (int mi=0; mi<2; ++mi) {
      const int row = (wid<<5) + (mi<<4) + r15;
      const int ch = (kk<<2) + q;
      const int chs = (ch & 24) | ((ch ^ (row & 7)) & 7);
      pa[mi] = *(const bf16x8*)(Ps + (row<<8) + (chs<<3));
    }
#pragma unroll
    for (int ni=0; ni<4; ++ni) {
      const int vrow = (ni<<4) + r15;
      const int ch = (kk<<2) + q;
      const int chs = (ch & 24) | ((ch ^ (vrow & 7)) & 7);
      const bf16x8 bv = *(const bf16x8*)(Vs + (vrow<<8) + (chs<<3));
      o[0][ni] = __builtin_amdgcn_mfma_f32_16x16x32_bf16(pa[0], bv, o[0][ni], 0,0,0);
      o[1][ni] = __builtin_amdgcn_mfma_f32_16x16x32_bf16(pa[1], bv, o[1][ni], 0,0,0);
    }
  }
#pragma unroll
  for (int mi=0; mi<2; ++mi)
#pragma unroll
    for (int ni=0; ni<4; ++ni)
#pragma unroll
      for (int r=0; r<4; ++r) {
        const long long m = mBase + (wid<<5) + (mi<<4) + (q<<2) + r;
        ao[m*512 + (h<<6) + (ni<<4) + r15] = f2bf(o[mi][ni][r]);
      }
}

// ---------------- double layernorm (wave-per-row) + column-sum partials + scp zero --------
__global__ __launch_bounds__(256) void ln64_k(
    const unsigned short* __restrict__ attno, const unsigned short* __restrict__ feat,
    const float* __restrict__ g1, const float* __restrict__ b1,
    const float* __restrict__ g2, const float* __restrict__ b2,
    unsigned short* __restrict__ att, float* __restrict__ colp, float* __restrict__ scp)
{
  __shared__ float cred[4][512];
  const int tid = threadIdx.x, lane = tid & 63, wid = tid >> 6;
  const int c0 = lane << 3;
  scp[((long long)blockIdx.x<<8) + tid] = 0.f;
  float g1v[8], b1v[8], g2v[8], b2v[8];
#pragma unroll
  for (int j=0;j<8;j++){ g1v[j]=g1[c0+j]; b1v[j]=b1[c0+j]; g2v[j]=g2[c0+j]; b2v[j]=b2[c0+j]; }
  float cacc[8];
#pragma unroll
  for (int j=0;j<8;j++) cacc[j]=0.f;
  for (int rr=0; rr<16; ++rr) {
    const long long row = ((long long)blockIdx.x<<6) + (rr<<2) + wid;
    const bf16x8 a = *(const bf16x8*)(attno + (row<<9) + c0);
    const bf16x8 f = *(const bf16x8*)(feat  + (row<<9) + c0);
    float xv[8]; float s=0.f, qs=0.f;
#pragma unroll
    for (int j=0;j<8;j++){ xv[j] = bf2f((unsigned short)a[j]) + bf2f((unsigned short)f[j]); s += xv[j]; qs += xv[j]*xv[j]; }
#pragma unroll
    for (int o=32;o;o>>=1){ s += __shfl_xor(s,o,64); qs += __shfl_xor(qs,o,64); }
    float m = s*(1.f/512.f);
    float rs = rsqrtf(qs*(1.f/512.f) - m*m + 1e-5f);
    float y[8]; s=0.f; qs=0.f;
#pragma unroll
    for (int j=0;j<8;j++){ y[j] = (xv[j]-m)*rs*g1v[j] + b1v[j]; s += y[j]; qs += y[j]*y[j]; }
#pragma unroll
    for (int o=32;o;o>>=1){ s += __shfl_xor(s,o,64); qs += __shfl_xor(qs,o,64); }
    m = s*(1.f/512.f);
    rs = rsqrtf(qs*(1.f/512.f) - m*m + 1e-5f);
    bf16x8 ov;
#pragma unroll
    for (int j=0;j<8;j++){ const float z = (y[j]-m)*rs*g2v[j] + b2v[j]; cacc[j] += z; ov[j] = (short)f2bf(z); }
    *(bf16x8*)(att + (row<<9) + c0) = ov;
  }
#pragma unroll
  for (int j=0;j<8;j++) cred[wid][c0+j] = cacc[j];
  __syncthreads();
  {
    const float v0 = cred[0][tid]+cred[1][tid]+cred[2][tid]+cred[3][tid];
    const float v1 = cred[0][tid+256]+cred[1][tid+256]+cred[2][tid+256]+cred[3][tid+256];
    colp[((long long)blockIdx.x<<9)+tid]     = v0;
    colp[((long long)blockIdx.x<<9)+tid+256] = v1;
  }
}

// ---------------- gates / moe stats / bag / classifier ----------------
__global__ __launch_bounds__(512) void meangates_k(const float* __restrict__ part,
    const float* __restrict__ gw, const float* __restrict__ gb, float* __restrict__ gates)
{
  __shared__ float mv[512];
  __shared__ float tmp[4];
  const int t = threadIdx.x;
  float s = 0.f;
  for (int b=0;b<256;b++) s += part[(b<<9)+t];
  mv[t] = s * (1.f/16384.f);
  __syncthreads();
  if (t < 4) {
    float a = gb[t];
    for (int d=0; d<512; ++d) a += mv[d]*gw[d*4+t];
    tmp[t] = a;
  }
  __syncthreads();
  if (t == 0) {
    const float m = fmaxf(fmaxf(tmp[0],tmp[1]),fmaxf(tmp[2],tmp[3]));
    float e[4]; float ss=0.f;
    for (int i=0;i<4;i++){ e[i]=__expf(tmp[i]-m); ss+=e[i]; }
    for (int i=0;i<4;i++) gates[i] = e[i]/ss;
  }
}

__global__ __launch_bounds__(1024) void moestat_k(const float* __restrict__ sc,
                                                  float* __restrict__ mstat, float* __restrict__ sstat)
{
  __shared__ float red[1024];
  const int e = blockIdx.x, t = threadIdx.x;
  const float* p = sc + e*16384;
  float m = -3.4e38f;
  for (int n=t; n<16384; n+=1024) m = fmaxf(m, p[n]);
  red[t] = m; __syncthreads();
  for (int o=512;o;o>>=1){ if (t<o) red[t]=fmaxf(red[t],red[t+o]); __syncthreads(); }
  m = red[0]; __syncthreads();
  float s = 0.f;
  for (int n=t; n<16384; n+=1024) s += __expf(p[n]-m);
  red[t] = s; __syncthreads();
  for (int o=512;o;o>>=1){ if (t<o) red[t]+=red[t+o]; __syncthreads(); }
  if (t==0){ mstat[e]=m; sstat[e]=red[0]; }
}

__global__ __launch_bounds__(256) void wbag_k(const unsigned short* __restrict__ att,
    const float* __restrict__ scp, const float* __restrict__ gates,
    const float* __restrict__ mstat, const float* __restrict__ sstat,
    float* __restrict__ part, float* __restrict__ dout)
{
  __shared__ float wrow[128];
  const int c = threadIdx.x;
  const long long r0 = (long long)blockIdx.x * 128;
  if (c < 128) {
    const long long n = r0 + c;
    float w = 0.f;
#pragma unroll
    for (int e=0;e<4;e++) w += gates[e]*__expf(scp[((long long)e<<14)+n]-mstat[e]) / sstat[e];
    wrow[c] = w;
    dout[514 + n] = w;
  }
  __syncthreads();
  float a0=0.f, a1=0.f;
  for (int r=0;r<128;r++){
    const float w = wrow[r];
    const unsigned short* p = att + ((r0+r)<<9);
    a0 += w*bf2f(p[c]); a1 += w*bf2f(p[c+256]);
  }
  part[((long long)blockIdx.x<<9)+c]     = a0;
  part[((long long)blockIdx.x<<9)+c+256] = a1;
}

__global__ __launch_bounds__(512) void cls2_k(const float* __restrict__ bagp,
    const float* __restrict__ w1, const float* __restrict__ b1,
    const float* __restrict__ w2, const float* __restrict__ b2,
    const float* __restrict__ w3, const float* __restrict__ b3, float* __restrict__ dout)
{
  __shared__ float bag[512]; __shared__ float c1[256]; __shared__ float c2[128];
  const int tid = threadIdx.x;
  float s = 0.f;
  for (int b=0;b<128;b++) s += bagp[(b<<9)+tid];
  bag[tid] = s; dout[tid] = s;
  __syncthreads();
  if (tid < 256) {
    float a = b1[tid];
    for (int d=0; d<512; ++d) a += bag[d]*w1[d*256+tid];
    c1[tid] = fmaxf(a, 0.f);
  }
  __syncthreads();
  if (tid < 128) {
    float a2 = b2[tid];
    for (int d=0; d<256; ++d) a2 += c1[d]*w2[d*128+tid];
    c2[tid] = fmaxf(a2, 0.f);
  }
  __syncthreads();
  if (tid < 2) {
    float a3 = b3[tid];
    for (int d=0; d<128; ++d) a3 += c2[d]*w3[d*2+tid];
    dout[512 + tid] = a3;
  }
}

extern "C" void kernel_launch(void* const* d_in, const int* in_sizes, int n_in,
                              void* d_out, int out_size, void* d_ws, size_t ws_size,
                              hipStream_t stream)
{
  (void)in_sizes; (void)n_in; (void)out_size; (void)ws_size;
  const float* x      = (const float*)d_in[0];
  const float* enc_w1 = (const float*)d_in[1];
  const float* enc_b1 = (const float*)d_in[2];
  const float* enc_w2 = (const float*)d_in[3];
  const float* enc_b2 = (const float*)d_in[4];
  const float* enc_w3 = (const float*)d_in[5];
  const float* enc_b3 = (const float*)d_in[6];
  const float* q_w    = (const float*)d_in[7];
  const float* q_b    = (const float*)d_in[8];
  const float* k_w    = (const float*)d_in[9];
  const float* k_b    = (const float*)d_in[10];
  const float* v_w    = (const float*)d_in[11];
  const float* v_b    = (const float*)d_in[12];
  const float* o_w    = (const float*)d_in[13];
  const float* o_b    = (const float*)d_in[14];
  const float* E_w    = (const float*)d_in[15];
  const float* F_w    = (const float*)d_in[16];
  const float* ln1_g  = (const float*)d_in[17];
  const float* ln1_b  = (const float*)d_in[18];
  const float* ln2_g  = (const float*)d_in[19];
  const float* ln2_b  = (const float*)d_in[20];
  const float* gate_w = (const float*)d_in[21];
  const float* gate_b = (const float*)d_in[22];
  const float* moe_w1 = (const float*)d_in[23];
  const float* moe_b1 = (const float*)d_in[24];
  const float* moe_w2 = (const float*)d_in[25];
  // d_in[26] = moe_b2: drops out of the row-softmax (shift invariance)
  const float* cls_w1 = (const float*)d_in[27];
  const float* cls_b1 = (const float*)d_in[28];
  const float* cls_w2 = (const float*)d_in[29];
  const float* cls_b2 = (const float*)d_in[30];
  const float* cls_w3 = (const float*)d_in[31];
  const float* cls_b3 = (const float*)d_in[32];

  char* ws = (char*)d_ws;
  const size_t MB = 1024*1024;
  unsigned short* x_bf  = (unsigned short*)(ws + 0);          // [16384][2048]  64MB
  unsigned short* h1    = (unsigned short*)(ws + 64*MB);      // [16384][1024]  32MB
  unsigned short* h2    = (unsigned short*)(ws + 0);          // 16MB (x_bf dead)
  unsigned short* feat  = (unsigned short*)(ws + 16*MB);      // 16MB
  unsigned short* qkv   = (unsigned short*)(ws + 32*MB);      // [16384][1536]  48MB (h1 dead)
  unsigned short* ao    = (unsigned short*)(ws + 80*MB);      // 16MB
  unsigned short* attno = (unsigned short*)(ws + 0);          // 16MB (h2 dead)
  unsigned short* att   = (unsigned short*)(ws + 96*MB);      // 16MB
  unsigned short* w1t   = (unsigned short*)(ws + 112*MB);                 // [1024][2048] 4MB
  unsigned short* w2t   = (unsigned short*)(ws + 116*MB);                 // 1MB
  unsigned short* w3t   = (unsigned short*)(ws + 117*MB);                 // 0.5MB
  unsigned short* qkvw  = (unsigned short*)(ws + 117*MB + 512*1024);      // 1.5MB
  unsigned short* owt   = (unsigned short*)(ws + 119*MB);                 // 0.5MB
  unsigned short* mwt   = (unsigned short*)(ws + 119*MB + 512*1024);      // 1MB
  float*  t1b   = (float*)(ws + 120*MB + 512*1024);                       // 0.5MB
  float*  redb  = (float*)(ws + 121*MB);                                  // 1MB
  unsigned short* Kcbf  = (unsigned short*)(ws + 122*MB);                 // 256KB
  unsigned short* Vctbf = (unsigned short*)(ws + 122*MB + 256*1024);      // 256KB
  float*  colp  = (float*)(ws + 122*MB + 512*1024);                       // [256][512] 512KB
  float*  bagp  = (float*)(ws + 123*MB);                                  // [128][512] 256KB
  float*  qkvb  = (float*)(ws + 123*MB + 256*1024);                       // 6KB
  float*  gatesp= (float*)(ws + 123*MB + 264*1024);
  float*  scp   = (float*)(ws + 123*MB + 268*1024);                       // [4][16384] 256KB
  float*  mstat = (float*)(ws + 123*MB + 524*1024);
  float*  sstat = (float*)(ws + 123*MB + 524*1024 + 64);
  float*  dout  = (float*)d_out;

  // ---- mega prep (t1, transposes, pad-zero, lane-contiguous x convert) ----
  prep_k<<<4033,256,0,stream>>>(x, x_bf, enc_w1, w1t, enc_w2, w2t,
                                enc_w3, q_w, k_w, v_w, o_w, w3t, qkvw, owt,
                                moe_w1, mwt, E_w, F_w, t1b, q_b, k_b, v_b, qkvb);

  // ---- encoder ----
  gemm4_k<1,false><<<dim3(4,64,1),512,0,stream>>>(x_bf, w1t, enc_b1, h1, nullptr,nullptr, 2048,2048,2048,1024);
  gemm5_k<1><<<dim3(4,128,1),256,0,stream>>>(h1, w2t, enc_b2, h2,   1024,1024,1024, 512);
  gemm5_k<1><<<dim3(4,128,1),256,0,stream>>>(h2, w3t, enc_b3, feat,  512, 512, 512, 512);
  // ---- QKV (merged, N=1536) ----
  gemm5_k<0><<<dim3(12,128,1),256,0,stream>>>(feat, qkvw, qkvb, qkv, 512,512,512,1536);
  // ---- linformer projections ----
  red_k<<<dim3(256,2),512,0,stream>>>(qkv, redb);
  kc_k <<<dim3(256,2),512,0,stream>>>(t1b, redb, Kcbf, Vctbf);
  // ---- fused attention ----
  attn_k<<<dim3(128,8),256,0,stream>>>(qkv, Kcbf, Vctbf, ao);
  // ---- output projection + residual + double LN (+ colsum partials + scp zero) ----
  gemm5_k<0><<<dim3(4,128,1),256,0,stream>>>(ao, owt, o_b, attno, 512,512,512,512);
  ln64_k<<<256,256,0,stream>>>(attno, feat, ln1_g, ln1_b, ln2_g, ln2_b, att, colp, scp);
  meangates_k<<<1,512,0,stream>>>(colp, gate_w, gate_b, gatesp);
  // ---- MoE expert attention: ONE merged N=1024 GEMM, tanh+dot fused in epilogue ----
  gemm4_k<0,true><<<dim3(4,64,1),512,0,stream>>>(att, mwt, moe_b1, nullptr, moe_w2, scp, 512,512,512,0);
  moestat_k<<<4,1024,0,stream>>>(scp, mstat, sstat);
  // ---- attn weights + bag partials (fused) + classifier ----
  wbag_k<<<128,256,0,stream>>>(att, scp, gatesp, mstat, sstat, bagp, dout);
  cls2_k<<<1,512,0,stream>>>(bagp, cls_w1, cls_b1, cls_w2, cls_b2, cls_w3, cls_b3, dout);
}

// Round 14
// 415.843 us; speedup vs baseline: 1.1621x; 1.0308x over previous
//
#include <hip/hip_runtime.h>

#define DI __device__ __forceinline__

DI float bf2f(unsigned short u){ unsigned int v = ((unsigned int)u)<<16; float f; __builtin_memcpy(&f,&v,4); return f; }
DI unsigned short f2bf(float f){ unsigned int v; __builtin_memcpy(&v,&f,4); v = v + 0x7FFFu + ((v>>16)&1u); return (unsigned short)(v>>16); }

typedef __attribute__((ext_vector_type(8))) short bf16x8;
typedef __attribute__((ext_vector_type(4))) short short4v;
typedef __attribute__((ext_vector_type(4))) float f32x4;

#define GLD_LDS16(src, dst) __builtin_amdgcn_global_load_lds( \
    (const __attribute__((address_space(1))) void*)(src), \
    (__attribute__((address_space(3))) void*)(dst), 16, 0, 0)

DI void barrier_() { asm volatile("" ::: "memory"); __builtin_amdgcn_s_barrier(); asm volatile("" ::: "memory"); }

// ---------------- gemm5: 128x128 tile, 4-phase counted-vmcnt pipeline (2 barriers/tile) ----
template<int ACT>
__global__ __launch_bounds__(256,2) void gemm5_k(
    const unsigned short* __restrict__ A, const unsigned short* __restrict__ Bt,
    const float* __restrict__ bias, unsigned short* __restrict__ C,
    int K, int lda, int ldb, int ldc)
{
  __shared__ unsigned short As[2][8192];
  __shared__ unsigned short Bs[2][8192];
  const int tid = threadIdx.x, lane = tid & 63, wid = tid >> 6;
  const int wm = wid >> 1, wn = wid & 1;
  const int q = lane >> 4, r15 = lane & 15;
  const int nx = gridDim.x;
  const int bid = blockIdx.x + nx*blockIdx.y;
  const int cpx = (nx*gridDim.y) >> 3;
  const int wg = (bid & 7)*cpx + (bid >> 3);
  const long long mBase = (long long)(wg / nx) << 7;
  const long long nBase = (long long)(wg % nx) << 7;

  f32x4 acc[4][4];
#pragma unroll
  for (int i=0;i<4;i++)
#pragma unroll
    for (int j=0;j<4;j++)
#pragma unroll
      for (int r=0;r<4;r++) acc[i][j][r] = 0.f;

  const int NT = K >> 6;

#define G5_STA(j, nb, kk) { const int d_ = tid + ((j)<<8); const int row_ = d_>>3, c_ = d_&7, sc_ = c_ ^ (row_&7); \
    GLD_LDS16(A + (mBase+row_)*(long long)lda + (kk) + (sc_<<3), &As[nb][d_<<3]); }
#define G5_STB(j, nb, kk) { const int d_ = tid + ((j)<<8); const int row_ = d_>>3, c_ = d_&7, sc_ = c_ ^ (row_&7); \
    GLD_LDS16(Bt + (nBase+row_)*(long long)ldb + (kk) + (sc_<<3), &Bs[nb][d_<<3]); }

  G5_STB(0,0,0); G5_STB(2,0,0); G5_STB(1,0,0); G5_STB(3,0,0);
  G5_STA(0,0,0); G5_STA(2,0,0); G5_STA(1,0,0); G5_STA(3,0,0);

  for (int t=0; t<NT; ++t) {
    const int b = t & 1, nb = b ^ 1;
    const bool more = (t+1 < NT);
    const int k1 = (t+1) << 6;
    bf16x8 aL[4], aH[4], bL[4], bH[4];

    asm volatile("s_waitcnt vmcnt(2)" ::: "memory");
    barrier_();
#pragma unroll
    for (int mi=0; mi<2; ++mi)
#pragma unroll
      for (int ks=0; ks<2; ++ks) {
        const int row = (wm<<6) + (mi<<4) + r15;
        const int ch = ((ks<<2)+q) ^ (row&7);
        aL[mi*2+ks] = *(const bf16x8*)&As[b][(row<<6) + (ch<<3)];
      }
#pragma unroll
    for (int ni=0; ni<2; ++ni)
#pragma unroll
      for (int ks=0; ks<2; ++ks) {
        const int col = (wn<<6) + (ni<<4) + r15;
        const int ch = ((ks<<2)+q) ^ (col&7);
        bL[ni*2+ks] = *(const bf16x8*)&Bs[b][(col<<6) + (ch<<3)];
      }
    if (more) { G5_STB(0,nb,k1); G5_STB(2,nb,k1); }
    __builtin_amdgcn_s_setprio(1);
#pragma unroll
    for (int mi=0; mi<2; ++mi)
#pragma unroll
      for (int ni=0; ni<2; ++ni)
#pragma unroll
        for (int ks=0; ks<2; ++ks)
          acc[mi][ni] = __builtin_amdgcn_mfma_f32_16x16x32_bf16(aL[mi*2+ks], bL[ni*2+ks], acc[mi][ni], 0,0,0);
    __builtin_amdgcn_s_setprio(0);

#pragma unroll
    for (int ni=0; ni<2; ++ni)
#pragma unroll
      for (int ks=0; ks<2; ++ks) {
        const int col = (wn<<6) + ((ni+2)<<4) + r15;
        const int ch = ((ks<<2)+q) ^ (col&7);
        bH[ni*2+ks] = *(const bf16x8*)&Bs[b][(col<<6) + (ch<<3)];
      }
    if (more) { G5_STB(1,nb,k1); G5_STB(3,nb,k1); }
    __builtin_amdgcn_s_setprio(1);
#pragma unroll
    for (int mi=0; mi<2; ++mi)
#pragma unroll
      for (int ni=0; ni<2; ++ni)
#pragma unroll
        for (int ks=0; ks<2; ++ks)
          acc[mi][ni+2] = __builtin_amdgcn_mfma_f32_16x16x32_bf16(aL[mi*2+ks], bH[ni*2+ks], acc[mi][ni+2], 0,0,0);
    __builtin_amdgcn_s_setprio(0);

    if (more) { asm volatile("s_waitcnt vmcnt(4)" ::: "memory"); }
    else      { asm volatile("s_waitcnt vmcnt(0)" ::: "memory"); }
    barrier_();
#pragma unroll
    for (int mi=0; mi<2; ++mi)
#pragma unroll
      for (int ks=0; ks<2; ++ks) {
        const int row = (wm<<6) + ((mi+2)<<4) + r15;
        const int ch = ((ks<<2)+q) ^ (row&7);
        aH[mi*2+ks] = *(const bf16x8*)&As[b][(row<<6) + (ch<<3)];
      }
    if (more) { G5_STA(0,nb,k1); G5_STA(2,nb,k1); }
    __builtin_amdgcn_s_setprio(1);
#pragma unroll
    for (int mi=0; mi<2; ++mi)
#pragma unroll
      for (int ni=0; ni<2; ++ni)
#pragma unroll
        for (int ks=0; ks<2; ++ks)
          acc[mi+2][ni] = __builtin_amdgcn_mfma_f32_16x16x32_bf16(aH[mi*2+ks], bL[ni*2+ks], acc[mi+2][ni], 0,0,0);
    __builtin_amdgcn_s_setprio(0);

    if (more) { G5_STA(1,nb,k1); G5_STA(3,nb,k1); }
    __builtin_amdgcn_s_setprio(1);
#pragma unroll
    for (int mi=0; mi<2; ++mi)
#pragma unroll
      for (int ni=0; ni<2; ++ni)
#pragma unroll
        for (int ks=0; ks<2; ++ks)
          acc[mi+2][ni+2] = __builtin_amdgcn_mfma_f32_16x16x32_bf16(aH[mi*2+ks], bH[ni*2+ks], acc[mi+2][ni+2], 0,0,0);
    __builtin_amdgcn_s_setprio(0);
  }
#undef G5_STA
#undef G5_STB

#pragma unroll
  for (int ni=0; ni<4; ++ni) {
    const long long n = nBase + (wn<<6) + (ni<<4) + r15;
    const float bval = bias[n];
#pragma unroll
    for (int mi=0; mi<4; ++mi) {
#pragma unroll
      for (int r=0; r<4; ++r) {
        const long long m = mBase + (wm<<6) + (mi<<4) + (q<<2) + r;
        float v = acc[mi][ni][r] + bval;
        if constexpr (ACT==1) v = fmaxf(v, 0.f);
        C[m*(long long)ldc + n] = f2bf(v);
      }
    }
  }
}

// ---------------- gemm4: 256x256 tile, 4-phase counted-vmcnt pipeline (2 barriers/tile) ----
template<int ACT, bool MOE>
__global__ __launch_bounds__(512,2) void gemm4_k(
    const unsigned short* __restrict__ A, const unsigned short* __restrict__ Bt,
    const float* __restrict__ bias, unsigned short* __restrict__ C,
    const float* __restrict__ w2, float* __restrict__ scp,
    int K, int lda, int ldb, int ldc)
{
  __shared__ unsigned short As[2][16384];
  __shared__ unsigned short Bs[2][16384];
  const int tid = threadIdx.x, lane = tid & 63, wid = tid >> 6;
  const int wm = wid >> 2, wn = wid & 3;
  const int q = lane >> 4, r15 = lane & 15;
  const int nx = gridDim.x;
  const int bid = blockIdx.x + nx*blockIdx.y;
  const int cpx = (nx*gridDim.y) >> 3;
  const int wg = (bid & 7)*cpx + (bid >> 3);
  const long long mBase = (long long)(wg / nx) << 8;
  const long long nBase = (long long)(wg % nx) << 8;

  f32x4 acc[8][4];
#pragma unroll
  for (int i=0;i<8;i++)
#pragma unroll
    for (int j=0;j<4;j++)
#pragma unroll
      for (int r=0;r<4;r++) acc[i][j][r] = 0.f;

  const int NT = K >> 6;

#define G4_STA(j, nb, kk) { const int d_ = tid + ((j)<<9); const int row_ = d_>>3, c_ = d_&7, sc_ = c_ ^ (row_&7); \
    GLD_LDS16(A + (mBase+row_)*(long long)lda + (kk) + (sc_<<3), &As[nb][d_<<3]); }
#define G4_STB(j, nb, kk) { const int d_ = tid + ((j)<<9); const int row_ = d_>>3, c_ = d_&7, sc_ = c_ ^ (row_&7); \
    GLD_LDS16(Bt + (nBase+row_)*(long long)ldb + (kk) + (sc_<<3), &Bs[nb][d_<<3]); }

  G4_STB(0,0,0); G4_STB(1,0,0); G4_STB(2,0,0); G4_STB(3,0,0);
  G4_STA(0,0,0); G4_STA(2,0,0); G4_STA(1,0,0); G4_STA(3,0,0);

  for (int t=0; t<NT; ++t) {
    const int b = t & 1, nb = b ^ 1;
    const bool more = (t+1 < NT);
    const int k1 = (t+1) << 6;
    bf16x8 aF[8], bL[4], bH[4];

    asm volatile("s_waitcnt vmcnt(2)" ::: "memory");
    barrier_();
#pragma unroll
    for (int mi=0; mi<4; ++mi)
#pragma unroll
      for (int ks=0; ks<2; ++ks) {
        const int row = (wm<<7) + (mi<<4) + r15;
        const int ch = ((ks<<2)+q) ^ (row&7);
        aF[mi*2+ks] = *(const bf16x8*)&As[b][(row<<6) + (ch<<3)];
      }
#pragma unroll
    for (int ni=0; ni<2; ++ni)
#pragma unroll
      for (int ks=0; ks<2; ++ks) {
        const int col = (wn<<6) + (ni<<4) + r15;
        const int ch = ((ks<<2)+q) ^ (col&7);
        bL[ni*2+ks] = *(const bf16x8*)&Bs[b][(col<<6) + (ch<<3)];
      }
    if (more) { G4_STB(0,nb,k1); G4_STB(1,nb,k1); }
    __builtin_amdgcn_s_setprio(1);
#pragma unroll
    for (int mi=0; mi<4; ++mi)
#pragma unroll
      for (int ni=0; ni<2; ++ni)
#pragma unroll
        for (int ks=0; ks<2; ++ks)
          acc[mi][ni] = __builtin_amdgcn_mfma_f32_16x16x32_bf16(aF[mi*2+ks], bL[ni*2+ks], acc[mi][ni], 0,0,0);
    __builtin_amdgcn_s_setprio(0);

#pragma unroll
    for (int ni=0; ni<2; ++ni)
#pragma unroll
      for (int ks=0; ks<2; ++ks) {
        const int col = (wn<<6) + ((ni+2)<<4) + r15;
        const int ch = ((ks<<2)+q) ^ (col&7);
        bH[ni*2+ks] = *(const bf16x8*)&Bs[b][(col<<6) + (ch<<3)];
      }
    if (more) { G4_STB(2,nb,k1); G4_STB(3,nb,k1); }
    __builtin_amdgcn_s_setprio(1);
#pragma unroll
    for (int mi=0; mi<4; ++mi)
#pragma unroll
      for (int ni=0; ni<2; ++ni)
#pragma unroll
        for (int ks=0; ks<2; ++ks)
          acc[mi][ni+2] = __builtin_amdgcn_mfma_f32_16x16x32_bf16(aF[mi*2+ks], bH[ni*2+ks], acc[mi][ni+2], 0,0,0);
    __builtin_amdgcn_s_setprio(0);

    if (more) { asm volatile("s_waitcnt vmcnt(4)" ::: "memory"); }
    else      { asm volatile("s_waitcnt vmcnt(0)" ::: "memory"); }
    barrier_();
#pragma unroll
    for (int mi=0; mi<4; ++mi)
#pragma unroll
      for (int ks=0; ks<2; ++ks) {
        const int row = (wm<<7) + ((mi+4)<<4) + r15;
        const int ch = ((ks<<2)+q) ^ (row&7);
        aF[mi*2+ks] = *(const bf16x8*)&As[b][(row<<6) + (ch<<3)];
      }
    if (more) { G4_STA(0,nb,k1); G4_STA(2,nb,k1); }
    __builtin_amdgcn_s_setprio(1);
#pragma unroll
    for (int mi=0; mi<4; ++mi)
#pragma unroll
      for (int ni=0; ni<2; ++ni)
#pragma unroll
        for (int ks=0; ks<2; ++ks)
          acc[mi+4][ni] = __builtin_amdgcn_mfma_f32_16x16x32_bf16(aF[mi*2+ks], bL[ni*2+ks], acc[mi+4][ni], 0,0,0);
    __builtin_amdgcn_s_setprio(0);

    if (more) { G4_STA(1,nb,k1); G4_STA(3,nb,k1); }
    __builtin_amdgcn_s_setprio(1);
#pragma unroll
    for (int mi=0; mi<4; ++mi)
#pragma unroll
      for (int ni=0; ni<2; ++ni)
#pragma unroll
        for (int ks=0; ks<2; ++ks)
          acc[mi+4][ni+2] = __builtin_amdgcn_mfma_f32_16x16x32_bf16(aF[mi*2+ks], bH[ni*2+ks], acc[mi+4][ni+2], 0,0,0);
    __builtin_amdgcn_s_setprio(0);
  }
#undef G4_STA
#undef G4_STB

  if constexpr (MOE) {
    const int e = (int)(nBase >> 8);
#pragma unroll
    for (int mi=0; mi<8; ++mi) {
#pragma unroll
      for (int r=0; r<4; ++r) {
        float p = 0.f;
#pragma unroll
        for (int ni=0; ni<4; ++ni) {
          const int n = (int)nBase + (wn<<6) + (ni<<4) + r15;
          const float v = acc[mi][ni][r] + bias[n];
          const float th = 1.f - 2.f/(__expf(2.f*v) + 1.f);
          p += th * w2[n];
        }
        p += __shfl_xor(p,1,64); p += __shfl_xor(p,2,64);
        p += __shfl_xor(p,4,64); p += __shfl_xor(p,8,64);
        if (r15 == 0) {
          const long long m = mBase + (wm<<7) + (mi<<4) + (q<<2) + r;
          atomicAdd(scp + ((long long)e<<14) + m, p);
        }
      }
    }
  } else {
#pragma unroll
    for (int ni=0; ni<4; ++ni) {
      const long long n = nBase + (wn<<6) + (ni<<4) + r15;
      const float bval = bias[n];
#pragma unroll
      for (int mi=0; mi<8; ++mi) {
#pragma unroll
        for (int r=0; r<4; ++r) {
          const long long m = mBase + (wm<<7) + (mi<<4) + (q<<2) + r;
          float v = acc[mi][ni][r] + bval;
          if constexpr (ACT==1) v = fmaxf(v, 0.f);
          C[m*(long long)ldc + n] = f2bf(v);
        }
      }
    }
  }
}

// ---------------- prep_w: t1 + weight transposes + qkvb (runs FIRST, low-BW) ----------------
DI void transpose64(const float* __restrict__ src, unsigned short* __restrict__ dst,
                    int K, int N, int Kpad, int k0, int n0, float (*tile)[65], int tid)
{
  const int c = tid & 63, rg = tid >> 6;
#pragma unroll
  for (int j=0;j<16;j++){
    const int r = (j<<2) + rg;
    const int k = k0 + r;
    tile[r][c] = (k < K) ? src[(long long)k*N + n0 + c] : 0.f;
  }
  __syncthreads();
#pragma unroll
  for (int j=0;j<16;j++){
    const int nn = (j<<2) + rg;
    dst[(long long)(n0+nn)*Kpad + k0 + c] = f2bf(tile[c][nn]);
  }
}

__global__ __launch_bounds__(256) void prep_w_k(
    const float* __restrict__ enc_w1, unsigned short* __restrict__ w1t,
    const float* __restrict__ enc_w2, unsigned short* __restrict__ w2t,
    const float* __restrict__ enc_w3, const float* __restrict__ q_w,
    const float* __restrict__ k_w, const float* __restrict__ v_w, const float* __restrict__ o_w,
    unsigned short* __restrict__ w3t, unsigned short* __restrict__ qkvw, unsigned short* __restrict__ owt,
    const float* __restrict__ moe_w1, unsigned short* __restrict__ mwt,
    const float* __restrict__ Ew, const float* __restrict__ Fw, float* __restrict__ t1,
    const float* __restrict__ qb, const float* __restrict__ kb, const float* __restrict__ vb,
    float* __restrict__ qkvb)
{
  __shared__ float tile[64][65];
  const int b = blockIdx.x, tid = threadIdx.x;
  if (b < 512) {
    const int k = b & 255, which = b >> 8, c = tid;
    const float* Wr = (which ? Fw : Ew) + (long long)c*10000;
    const float ksc = 39.0625f, inv = 1.f/39.0625f;
    const float sf = (k + 0.5f)*ksc - 0.5f;
    int ilo = (int)ceilf(sf - ksc); if (ilo < 0) ilo = 0;
    int ihi = (int)floorf(sf + ksc); if (ihi > 9999) ihi = 9999;
    float acc = 0.f, wsum = 0.f;
    int i = ilo;
    for (; i + 8 <= ihi + 1; i += 8) {
      float v[8];
#pragma unroll
      for (int j=0;j<8;j++) v[j] = Wr[i+j];
#pragma unroll
      for (int j=0;j<8;j++){
        const float w = fmaxf(1.f - fabsf(sf - (float)(i+j))*inv, 0.f);
        acc += w*v[j]; wsum += w;
      }
    }
    for (; i <= ihi; ++i) {
      const float w = fmaxf(1.f - fabsf(sf - (float)i)*inv, 0.f);
      acc += w * Wr[i]; wsum += w;
    }
    t1[(which*256 + k)*256 + c] = acc / wsum;
  } else if (b < 1024) {
    const int bb = b - 512;
    transpose64(enc_w1, w1t, 2000, 1024, 2048, (bb&31)<<6, (bb>>5)<<6, tile, tid);
  } else if (b < 1152) {
    const int bb = b - 1024;
    transpose64(enc_w2, w2t, 1024, 512, 1024, (bb&15)<<6, (bb>>4)<<6, tile, tid);
  } else if (b < 1472) {
    const int bb = b - 1152;
    const int z = bb >> 6, r = bb & 63;
    const float* s = (z==0)?enc_w3:(z==1)?q_w:(z==2)?k_w:(z==3)?v_w:o_w;
    unsigned short* d = (z==0)?w3t:(z==1)?qkvw:(z==2)?(qkvw+512*512):(z==3)?(qkvw+1024*512):owt;
    transpose64(s, d, 512, 512, 512, (r&7)<<6, (r>>3)<<6, tile, tid);
  } else if (b < 1600) {
    const int bb = b - 1472;
    const int z = bb >> 5, r = bb & 31;
    transpose64(moe_w1 + (long long)z*512*256, mwt + (long long)z*256*512,
                512, 256, 512, (r&7)<<6, (r>>3)<<6, tile, tid);
  } else {
#pragma unroll
    for (int i=0;i<6;i++){
      const int idx = i*256 + tid;
      const int wq = idx >> 9, off = idx & 511;
      const float* src = (wq==0)?qb:(wq==1)?kb:vb;
      qkvb[idx] = src[off];
    }
  }
}

// ---------------- xcvt: pad-zero + lane-contiguous x convert (runs SECOND) ----------------
__global__ __launch_bounds__(256) void xcvt_k(const float* __restrict__ x, unsigned short* __restrict__ xb)
{
  const int b = blockIdx.x, tid = threadIdx.x;
  if (b < 384) {
    const int p = b*256 + tid;                   // 0..98303
    const int row = p / 6, cc = p - row*6;
    bf16x8 z8;
#pragma unroll
    for (int j=0;j<8;j++) z8[j]=0;
    *(bf16x8*)(xb + (long long)row*2048 + 2000 + cc*8) = z8;
  } else {
    const int bb = b - 384;                      // 0..2047
    const long long base = (long long)bb*256 + tid;
#pragma unroll
    for (int j=0;j<16;j++){
      const long long id = base + (long long)j*524288;
      if (id < 8192000) {
        const float4 f = *((const float4*)x + id);
        const long long row = id / 500;
        const int col = (int)(id - row*500);
        short4v o;
        o[0]=(short)f2bf(f.x); o[1]=(short)f2bf(f.y); o[2]=(short)f2bf(f.z); o[3]=(short)f2bf(f.w);
        *(short4v*)(xb + row*2048 + (long long)col*4) = o;
      }
    }
  }
}

// ---------------- linformer projection helpers ----------------
__global__ __launch_bounds__(512) void red_k(const unsigned short* __restrict__ qkv,
                                             float* __restrict__ red)
{
  const int c = blockIdx.x, which = blockIdx.y, j = threadIdx.x;
  const unsigned short* X = qkv + (which ? 1024 : 512);
  int nlo = 64*c - 32; if (nlo < 0) nlo = 0;
  int nhi = 64*c + 95; if (nhi > 16383) nhi = 16383;
  float acc = 0.f;
  for (int n=nlo; n<=nhi; ++n) {
    float sf = (n + 0.5f)*0.015625f - 0.5f;
    sf = fminf(fmaxf(sf, 0.f), 255.f);
    const int c0 = (int)sf;
    const float f = sf - (float)c0;
    float w = 0.f;
    if (c == c0) w = 1.f - f;
    else if (c == c0+1) w = f;
    if (w != 0.f) acc += w * bf2f(X[(long long)n*1536 + j]);
  }
  red[(which*256 + c)*512 + j] = acc;
}

__global__ __launch_bounds__(512) void kc_k(const float* __restrict__ t1, const float* __restrict__ red,
                                            unsigned short* __restrict__ Kc, unsigned short* __restrict__ Vct)
{
  const int k = blockIdx.x, which = blockIdx.y, j = threadIdx.x;
  const float* T = t1 + (which*256 + k)*256;
  const float* R = red + which*131072;
  float acc = 0.f;
  for (int c=0; c<256; ++c) acc += T[c] * R[c*512 + j];
  const int h = j >> 6, d = j & 63;
  if (which == 0) Kc [(h<<14) + (k<<6) + d] = f2bf(acc);
  else            Vct[(h<<14) + (d<<8) + k] = f2bf(acc);
}

// ---------------- fused linformer attention ----------------
__global__ __launch_bounds__(256) void attn_k(
    const unsigned short* __restrict__ Qg, const unsigned short* __restrict__ Kc,
    const unsigned short* __restrict__ Vct, unsigned short* __restrict__ ao)
{
  __shared__ unsigned short Ks[16384];
  __shared__ unsigned short Vs[16384];
  __shared__ unsigned short Ps[32768];
  const int h = blockIdx.y;
  const long long mBase = (long long)blockIdx.x << 7;
  const int tid = threadIdx.x, lane = tid & 63, wid = tid >> 6;
  const int q = lane >> 4, r15 = lane & 15;

#pragma unroll
  for (int it=0; it<8; ++it) {
    const int dbase = (it<<8) + (wid<<6);
    const int d = dbase + lane;
    {
      const int row = d >> 3, cc = d & 7, sc = cc ^ (row & 7);
      GLD_LDS16(Kc + (h<<14) + (row<<6) + (sc<<3), Ks + (dbase<<3));
    }
    {
      const int row = d >> 5, cc = d & 31, sc = (cc & 24) | ((cc ^ (row & 7)) & 7);
      GLD_LDS16(Vct + (h<<14) + (row<<8) + (sc<<3), Vs + (dbase<<3));
    }
  }
  __syncthreads();

  f32x4 acc[2][16];
#pragma unroll
  for (int mi=0;mi<2;mi++)
#pragma unroll
    for (int ni=0;ni<16;ni++)
#pragma unroll
      for (int r=0;r<4;r++) acc[mi][ni][r] = 0.f;

#pragma unroll
  for (int ks=0; ks<2; ++ks) {
    bf16x8 af[2];
#pragma unroll
    for (int mi=0; mi<2; ++mi) {
      const long long m = mBase + (wid<<5) + (mi<<4) + r15;
      af[mi] = *(const bf16x8*)(Qg + m*1536 + (h<<6) + (ks<<5) + (q<<3));
    }
#pragma unroll
    for (int ni=0; ni<16; ++ni) {
      const int col = (ni<<4) + r15;
      const int ch = ((ks<<2)+q) ^ (col&7);
      const bf16x8 bv = *(const bf16x8*)(Ks + (col<<6) + (ch<<3));
      acc[0][ni] = __builtin_amdgcn_mfma_f32_16x16x32_bf16(af[0], bv, acc[0][ni], 0,0,0);
      acc[1][ni] = __builtin_amdgcn_mfma_f32_16x16x32_bf16(af[1], bv, acc[1][ni], 0,0,0);
    }
  }

#pragma unroll
  for (int mi=0; mi<2; ++mi) {
#pragma unroll
    for (int r=0; r<4; ++r) {
      float mx = -3.4e38f;
#pragma unroll
      for (int ni=0; ni<16; ++ni) mx = fmaxf(mx, acc[mi][ni][r]);
      mx = fmaxf(mx, __shfl_xor(mx,1,64)); mx = fmaxf(mx, __shfl_xor(mx,2,64));
      mx = fmaxf(mx, __shfl_xor(mx,4,64)); mx = fmaxf(mx, __shfl_xor(mx,8,64));
      float s = 0.f;
#pragma unroll
      for (int ni=0; ni<16; ++ni) {
        const float e = __expf((acc[mi][ni][r] - mx)*0.125f);
        acc[mi][ni][r] = e; s += e;
      }
      s += __shfl_xor(s,1,64); s += __shfl_xor(s,2,64);
      s += __shfl_xor(s,4,64); s += __shfl_xor(s,8,64);
      const float inv = 1.f / s;
      const int row = (wid<<5) + (mi<<4) + (q<<2) + r;
#pragma unroll
      for (int ni=0; ni<16; ++ni) {
        const int col = (ni<<4) + r15;
        const int ch = col >> 3;
        const int chs = (ch & 24) | ((ch ^ (row & 7)) & 7);
        Ps[(row<<8) + (chs<<3) + (col&7)] = f2bf(acc[mi][ni][r]*inv);
      }
    }
  }
  __syncthreads();

  f32x4 o[2][4];
#pragma unroll
  for (int mi=0;mi<2;mi++)
#pragma unroll
    for (int ni=0;ni<4;ni++)
#pragma unroll
      for (int r=0;r<4;r++) o[mi][ni][r] = 0.f;

#pragma unroll
  for (int kk=0; kk<8; ++kk) {
    bf16x8 pa[2];
#pragma unroll
    for (int mi=0; mi<2; ++mi) {
      const int row = (wid<<5) + (mi<<4) + r15;
      const int ch = (kk<<2) + q;
      const int chs = (ch & 24) | ((ch ^ (row & 7)) & 7);
      pa[mi] = *(const bf16x8*)(Ps + (row<<8) + (chs<<3));
    }
#pragma unroll
    for (int ni=0; ni<4; ++ni) {
      const int vrow = (ni<<4) + r15;
      const int ch = (kk<<2) + q;
      const int chs = (ch & 24) | ((ch ^ (vrow & 7)) & 7);
      const bf16x8 bv = *(const bf16x8*)(Vs + (vrow<<8) + (chs<<3));
      o[0][ni] = __builtin_amdgcn_mfma_f32_16x16x32_bf16(pa[0], bv, o[0][ni], 0,0,0);
      o[1][ni] = __builtin_amdgcn_mfma_f32_16x16x32_bf16(pa[1], bv, o[1][ni], 0,0,0);
    }
  }
#pragma unroll
  for (int mi=0; mi<2; ++mi)
#pragma unroll
    for (int ni=0; ni<4; ++ni)
#pragma unroll
      for (int r=0; r<4; ++r) {
        const long long m = mBase + (wid<<5) + (mi<<4) + (q<<2) + r;
        ao[m*512 + (h<<6) + (ni<<4) + r15] = f2bf(o[mi][ni][r]);
      }
}

// ---------------- double layernorm (wave-per-row) + column-sum partials + scp zero --------
__global__ __launch_bounds__(256) void ln64_k(
    const unsigned short* __restrict__ attno, const unsigned short* __restrict__ feat,
    const float* __restrict__ g1, const float* __restrict__ b1,
    const float* __restrict__ g2, const float* __restrict__ b2,
    unsigned short* __restrict__ att, float* __restrict__ colp, float* __restrict__ scp)
{
  __shared__ float cred[4][512];
  const int tid = threadIdx.x, lane = tid & 63, wid = tid >> 6;
  const int c0 = lane << 3;
  scp[((long long)blockIdx.x<<8) + tid] = 0.f;
  float g1v[8], b1v[8], g2v[8], b2v[8];
#pragma unroll
  for (int j=0;j<8;j++){ g1v[j]=g1[c0+j]; b1v[j]=b1[c0+j]; g2v[j]=g2[c0+j]; b2v[j]=b2[c0+j]; }
  float cacc[8];
#pragma unroll
  for (int j=0;j<8;j++) cacc[j]=0.f;
  for (int rr=0; rr<16; ++rr) {
    const long long row = ((long long)blockIdx.x<<6) + (rr<<2) + wid;
    const bf16x8 a = *(const bf16x8*)(attno + (row<<9) + c0);
    const bf16x8 f = *(const bf16x8*)(feat  + (row<<9) + c0);
    float xv[8]; float s=0.f, qs=0.f;
#pragma unroll
    for (int j=0;j<8;j++){ xv[j] = bf2f((unsigned short)a[j]) + bf2f((unsigned short)f[j]); s += xv[j]; qs += xv[j]*xv[j]; }
#pragma unroll
    for (int o=32;o;o>>=1){ s += __shfl_xor(s,o,64); qs += __shfl_xor(qs,o,64); }
    float m = s*(1.f/512.f);
    float rs = rsqrtf(qs*(1.f/512.f) - m*m + 1e-5f);
    float y[8]; s=0.f; qs=0.f;
#pragma unroll
    for (int j=0;j<8;j++){ y[j] = (xv[j]-m)*rs*g1v[j] + b1v[j]; s += y[j]; qs += y[j]*y[j]; }
#pragma unroll
    for (int o=32;o;o>>=1){ s += __shfl_xor(s,o,64); qs += __shfl_xor(qs,o,64); }
    m = s*(1.f/512.f);
    rs = rsqrtf(qs*(1.f/512.f) - m*m + 1e-5f);
    bf16x8 ov;
#pragma unroll
    for (int j=0;j<8;j++){ const float z = (y[j]-m)*rs*g2v[j] + b2v[j]; cacc[j] += z; ov[j] = (short)f2bf(z); }
    *(bf16x8*)(att + (row<<9) + c0) = ov;
  }
#pragma unroll
  for (int j=0;j<8;j++) cred[wid][c0+j] = cacc[j];
  __syncthreads();
  {
    const float v0 = cred[0][tid]+cred[1][tid]+cred[2][tid]+cred[3][tid];
    const float v1 = cred[0][tid+256]+cred[1][tid+256]+cred[2][tid+256]+cred[3][tid+256];
    colp[((long long)blockIdx.x<<9)+tid]     = v0;
    colp[((long long)blockIdx.x<<9)+tid+256] = v1;
  }
}

// ---------------- gates / moe stats / bag / classifier ----------------
__global__ __launch_bounds__(512) void meangates_k(const float* __restrict__ part,
    const float* __restrict__ gw, const float* __restrict__ gb, float* __restrict__ gates)
{
  __shared__ float mv[512];
  __shared__ float tmp[4];
  const int t = threadIdx.x;
  float s = 0.f;
  for (int b=0;b<256;b++) s += part[(b<<9)+t];
  mv[t] = s * (1.f/16384.f);
  __syncthreads();
  if (t < 4) {
    float a = gb[t];
    for (int d=0; d<512; ++d) a += mv[d]*gw[d*4+t];
    tmp[t] = a;
  }
  __syncthreads();
  if (t == 0) {
    const float m = fmaxf(fmaxf(tmp[0],tmp[1]),fmaxf(tmp[2],tmp[3]));
    float e[4]; float ss=0.f;
    for (int i=0;i<4;i++){ e[i]=__expf(tmp[i]-m); ss+=e[i]; }
    for (int i=0;i<4;i++) gates[i] = e[i]/ss;
  }
}

__global__ __launch_bounds__(1024) void moestat_k(const float* __restrict__ sc,
                                                  float* __restrict__ mstat, float* __restrict__ sstat)
{
  __shared__ float red[1024];
  const int e = blockIdx.x, t = threadIdx.x;
  const float* p = sc + e*16384;
  float m = -3.4e38f;
  for (int n=t; n<16384; n+=1024) m = fmaxf(m, p[n]);
  red[t] = m; __syncthreads();
  for (int o=512;o;o>>=1){ if (t<o) red[t]=fmaxf(red[t],red[t+o]); __syncthreads(); }
  m = red[0]; __syncthreads();
  float s = 0.f;
  for (int n=t; n<16384; n+=1024) s += __expf(p[n]-m);
  red[t] = s; __syncthreads();
  for (int o=512;o;o>>=1){ if (t<o) red[t]+=red[t+o]; __syncthreads(); }
  if (t==0){ mstat[e]=m; sstat[e]=red[0]; }
}

__global__ __launch_bounds__(256) void wbag_k(const unsigned short* __restrict__ att,
    const float* __restrict__ scp, const float* __restrict__ gates,
    const float* __restrict__ mstat, const float* __restrict__ sstat,
    float* __restrict__ part, float* __restrict__ dout)
{
  __shared__ float wrow[128];
  const int c = threadIdx.x;
  const long long r0 = (long long)blockIdx.x * 128;
  if (c < 128) {
    const long long n = r0 + c;
    float w = 0.f;
#pragma unroll
    for (int e=0;e<4;e++) w += gates[e]*__expf(scp[((long long)e<<14)+n]-mstat[e]) / sstat[e];
    wrow[c] = w;
    dout[514 + n] = w;
  }
  __syncthreads();
  float a0=0.f, a1=0.f;
  for (int r=0;r<128;r++){
    const float w = wrow[r];
    const unsigned short* p = att + ((r0+r)<<9);
    a0 += w*bf2f(p[c]); a1 += w*bf2f(p[c+256]);
  }
  part[((long long)blockIdx.x<<9)+c]     = a0;
  part[((long long)blockIdx.x<<9)+c+256] = a1;
}

__global__ __launch_bounds__(512) void cls2_k(const float* __restrict__ bagp,
    const float* __restrict__ w1, const float* __restrict__ b1,
    const float* __restrict__ w2, const float* __restrict__ b2,
    const float* __restrict__ w3, const float* __restrict__ b3, float* __restrict__ dout)
{
  __shared__ float bag[512]; __shared__ float c1[256]; __shared__ float c2[128];
  const int tid = threadIdx.x;
  float s = 0.f;
  for (int b=0;b<128;b++) s += bagp[(b<<9)+tid];
  bag[tid] = s; dout[tid] = s;
  __syncthreads();
  if (tid < 256) {
    float a = b1[tid];
    for (int d=0; d<512; ++d) a += bag[d]*w1[d*256+tid];
    c1[tid] = fmaxf(a, 0.f);
  }
  __syncthreads();
  if (tid < 128) {
    float a2 = b2[tid];
    for (int d=0; d<256; ++d) a2 += c1[d]*w2[d*128+tid];
    c2[tid] = fmaxf(a2, 0.f);
  }
  __syncthreads();
  if (tid < 2) {
    float a3 = b3[tid];
    for (int d=0; d<128; ++d) a3 += c2[d]*w3[d*2+tid];
    dout[512 + tid] = a3;
  }
}

extern "C" void kernel_launch(void* const* d_in, const int* in_sizes, int n_in,
                              void* d_out, int out_size, void* d_ws, size_t ws_size,
                              hipStream_t stream)
{
  (void)in_sizes; (void)n_in; (void)out_size; (void)ws_size;
  const float* x      = (const float*)d_in[0];
  const float* enc_w1 = (const float*)d_in[1];
  const float* enc_b1 = (const float*)d_in[2];
  const float* enc_w2 = (const float*)d_in[3];
  const float* enc_b2 = (const float*)d_in[4];
  const float* enc_w3 = (const float*)d_in[5];
  const float* enc_b3 = (const float*)d_in[6];
  const float* q_w    = (const float*)d_in[7];
  const float* q_b    = (const float*)d_in[8];
  const float* k_w    = (const float*)d_in[9];
  const float* k_b    = (const float*)d_in[10];
  const float* v_w    = (const float*)d_in[11];
  const float* v_b    = (const float*)d_in[12];
  const float* o_w    = (const float*)d_in[13];
  const float* o_b    = (const float*)d_in[14];
  const float* E_w    = (const float*)d_in[15];
  const float* F_w    = (const float*)d_in[16];
  const float* ln1_g  = (const float*)d_in[17];
  const float* ln1_b  = (const float*)d_in[18];
  const float* ln2_g  = (const float*)d_in[19];
  const float* ln2_b  = (const float*)d_in[20];
  const float* gate_w = (const float*)d_in[21];
  const float* gate_b = (const float*)d_in[22];
  const float* moe_w1 = (const float*)d_in[23];
  const float* moe_b1 = (const float*)d_in[24];
  const float* moe_w2 = (const float*)d_in[25];
  // d_in[26] = moe_b2: drops out of the row-softmax (shift invariance)
  const float* cls_w1 = (const float*)d_in[27];
  const float* cls_b1 = (const float*)d_in[28];
  const float* cls_w2 = (const float*)d_in[29];
  const float* cls_b2 = (const float*)d_in[30];
  const float* cls_w3 = (const float*)d_in[31];
  const float* cls_b3 = (const float*)d_in[32];

  char* ws = (char*)d_ws;
  const size_t MB = 1024*1024;
  unsigned short* x_bf  = (unsigned short*)(ws + 0);          // [16384][2048]  64MB
  unsigned short* h1    = (unsigned short*)(ws + 64*MB);      // [16384][1024]  32MB
  unsigned short* h2    = (unsigned short*)(ws + 0);          // 16MB (x_bf dead)
  unsigned short* feat  = (unsigned short*)(ws + 16*MB);      // 16MB
  unsigned short* qkv   = (unsigned short*)(ws + 32*MB);      // [16384][1536]  48MB (h1 dead)
  unsigned short* ao    = (unsigned short*)(ws + 80*MB);      // 16MB
  unsigned short* attno = (unsigned short*)(ws + 0);          // 16MB (h2 dead)
  unsigned short* att   = (unsigned short*)(ws + 96*MB);      // 16MB
  unsigned short* w1t   = (unsigned short*)(ws + 112*MB);                 // [1024][2048] 4MB
  unsigned short* w2t   = (unsigned short*)(ws + 116*MB);                 // 1MB
  unsigned short* w3t   = (unsigned short*)(ws + 117*MB);                 // 0.5MB
  unsigned short* qkvw  = (unsigned short*)(ws + 117*MB + 512*1024);      // 1.5MB
  unsigned short* owt   = (unsigned short*)(ws + 119*MB);                 // 0.5MB
  unsigned short* mwt   = (unsigned short*)(ws + 119*MB + 512*1024);      // 1MB
  float*  t1b   = (float*)(ws + 120*MB + 512*1024);                       // 0.5MB
  float*  redb  = (float*)(ws + 121*MB);                                  // 1MB
  unsigned short* Kcbf  = (unsigned short*)(ws + 122*MB);                 // 256KB
  unsigned short* Vctbf = (unsigned short*)(ws + 122*MB + 256*1024);      // 256KB
  float*  colp  = (float*)(ws + 122*MB + 512*1024);                       // [256][512] 512KB
  float*  bagp  = (float*)(ws + 123*MB);                                  // [128][512] 256KB
  float*  qkvb  = (float*)(ws + 123*MB + 256*1024);                       // 6KB
  float*  gatesp= (float*)(ws + 123*MB + 264*1024);
  float*  scp   = (float*)(ws + 123*MB + 268*1024);                       // [4][16384] 256KB
  float*  mstat = (float*)(ws + 123*MB + 524*1024);
  float*  sstat = (float*)(ws + 123*MB + 524*1024 + 64);
  float*  dout  = (float*)d_out;

  // ---- weight prep FIRST (latency-bound; absorbs harness poison-fill writeback window) ----
  prep_w_k<<<1601,256,0,stream>>>(enc_w1, w1t, enc_w2, w2t,
                                  enc_w3, q_w, k_w, v_w, o_w, w3t, qkvw, owt,
                                  moe_w1, mwt, E_w, F_w, t1b, q_b, k_b, v_b, qkvb);
  // ---- x convert SECOND (bandwidth-bound; runs after writebacks drain) ----
  xcvt_k<<<2432,256,0,stream>>>(x, x_bf);

  // ---- encoder ----
  gemm4_k<1,false><<<dim3(4,64,1),512,0,stream>>>(x_bf, w1t, enc_b1, h1, nullptr,nullptr, 2048,2048,2048,1024);
  gemm5_k<1><<<dim3(4,128,1),256,0,stream>>>(h1, w2t, enc_b2, h2,   1024,1024,1024, 512);
  gemm5_k<1><<<dim3(4,128,1),256,0,stream>>>(h2, w3t, enc_b3, feat,  512, 512, 512, 512);
  // ---- QKV (merged, N=1536) ----
  gemm5_k<0><<<dim3(12,128,1),256,0,stream>>>(feat, qkvw, qkvb, qkv, 512,512,512,1536);
  // ---- linformer projections ----
  red_k<<<dim3(256,2),512,0,stream>>>(qkv, redb);
  kc_k <<<dim3(256,2),512,0,stream>>>(t1b, redb, Kcbf, Vctbf);
  // ---- fused attention ----
  attn_k<<<dim3(128,8),256,0,stream>>>(qkv, Kcbf, Vctbf, ao);
  // ---- output projection + residual + double LN (+ colsum partials + scp zero) ----
  gemm5_k<0><<<dim3(4,128,1),256,0,stream>>>(ao, owt, o_b, attno, 512,512,512,512);
  ln64_k<<<256,256,0,stream>>>(attno, feat, ln1_g, ln1_b, ln2_g, ln2_b, att, colp, scp);
  meangates_k<<<1,512,0,stream>>>(colp, gate_w, gate_b, gatesp);
  // ---- MoE expert attention: ONE merged N=1024 GEMM, tanh+dot fused in epilogue ----
  gemm4_k<0,true><<<dim3(4,64,1),512,0,stream>>>(att, mwt, moe_b1, nullptr, moe_w2, scp, 512,512,512,0);
  moestat_k<<<4,1024,0,stream>>>(scp, mstat, sstat);
  // ---- attn weights + bag partials (fused) + classifier ----
  wbag_k<<<128,256,0,stream>>>(att, scp, gatesp, mstat, sstat, bagp, dout);
  cls2_k<<<1,512,0,stream>>>(bagp, cls_w1, cls_b1, cls_w2, cls_b2, cls_w3, cls_b3, dout);
}